// Round 3
// baseline (617.215 us; speedup 1.0000x reference)
//
#include <hip/hip_runtime.h>
#include <stdint.h>

// ---------------------------------------------------------------------------
// EncoderBlock: pre-norm transformer block, MI355X (gfx950).
// External dtype: FP32 (per reference). Internal: bf16 MFMA, fp32 accum,
// fp32 residual stream.
// B=2 S=2048 D=1024 H=16 DK=64 DFF=4096 WINDOW=128 GLOBAL=16
// ---------------------------------------------------------------------------

typedef unsigned short u16;
typedef unsigned int   u32;
typedef __attribute__((ext_vector_type(8))) short  short8;  // 8 bf16 (4 VGPRs)
typedef __attribute__((ext_vector_type(4))) float  f32x4;

#define S_LEN   2048
#define D_MODEL 1024
#define ROWS    4096   // B*S

__device__ __forceinline__ float bf2f(u16 u) {
  union { u32 i; float f; } v; v.i = ((u32)u) << 16; return v.f;
}
__device__ __forceinline__ float bflo(u32 u) {
  union { u32 i; float f; } v; v.i = u << 16; return v.f;
}
__device__ __forceinline__ float bfhi(u32 u) {
  union { u32 i; float f; } v; v.i = u & 0xffff0000u; return v.f;
}
__device__ __forceinline__ u16 f2bf(float f) {
  union { float f; u32 i; } v; v.f = f;
  u32 r = v.i + 0x7fffu + ((v.i >> 16) & 1u);
  return (u16)(r >> 16);
}

// ---------------------------------------------------------------------------
// GEMM: C[M,N] = A[M,K] @ B[K,N] (+bias, opt gelu/residual). A, Bt are bf16
// (Bt = B^T, K contiguous). bias/res fp32. OUTF: 0 = bf16 out, 1 = fp32 out.
// m93 structure: 128x128 tile, BK=32, 4 waves x (4x4) mfma_f32_16x16x32_bf16.
// EPI: 0=bias, 1=bias+gelu, 2=bias+residual.
// Cf and res may alias element-wise (same idx read->write per thread).
// ---------------------------------------------------------------------------
template <int EPI, int OUTF>
__global__ __launch_bounds__(256) void gemm_bt(
    const u16* __restrict__ A, const u16* __restrict__ Bt,
    const float* __restrict__ bias, const float* res,
    u16* Cb, float* Cf, int M, int N, int K)
{
  __shared__ __attribute__((aligned(16))) u16 As[128 * 32];
  __shared__ __attribute__((aligned(16))) u16 Bs[128 * 32];
  const int tid  = threadIdx.x;
  const int wave = tid >> 6;
  const int lane = tid & 63;
  const int bm = blockIdx.y * 128;
  const int bn = blockIdx.x * 128;
  const int wr = (wave >> 1) * 64;   // wave row offset in tile
  const int wc = (wave & 1) * 64;    // wave col offset in tile
  const int lm = lane & 15;
  const int kq = lane >> 4;          // 0..3 (k-quad)

  f32x4 acc[4][4];
#pragma unroll
  for (int i = 0; i < 4; ++i)
#pragma unroll
    for (int j = 0; j < 4; ++j) acc[i][j] = (f32x4){0.f, 0.f, 0.f, 0.f};

  // staging: thread -> (row = wave*16 + (lane>>2), kc = (lane&3)*8), + row+64.
  const int srow = wave * 16 + (lane >> 2);
  const int skc  = (lane & 3) * 8;
  const u16* gA = A  + (size_t)(bm + srow) * K + skc;
  const u16* gB = Bt + (size_t)(bn + srow) * K + skc;
  u16* sA0 = &As[srow * 32 + skc];
  u16* sA1 = &As[(srow + 64) * 32 + skc];
  u16* sB0 = &Bs[srow * 32 + skc];
  u16* sB1 = &Bs[(srow + 64) * 32 + skc];

  for (int k0 = 0; k0 < K; k0 += 32) {
    uint4 a0 = *(const uint4*)(gA + k0);
    uint4 a1 = *(const uint4*)(gA + (size_t)64 * K + k0);
    uint4 b0 = *(const uint4*)(gB + k0);
    uint4 b1 = *(const uint4*)(gB + (size_t)64 * K + k0);
    __syncthreads();   // previous iteration's ds_reads complete
    *(uint4*)sA0 = a0;
    *(uint4*)sA1 = a1;
    *(uint4*)sB0 = b0;
    *(uint4*)sB1 = b1;
    __syncthreads();   // stores visible to all waves

    short8 af[4], bfv[4];
#pragma unroll
    for (int ti = 0; ti < 4; ++ti)
      af[ti] = *(const short8*)&As[(wr + ti * 16 + lm) * 32 + kq * 8];
#pragma unroll
    for (int tj = 0; tj < 4; ++tj)
      bfv[tj] = *(const short8*)&Bs[(wc + tj * 16 + lm) * 32 + kq * 8];
#pragma unroll
    for (int ti = 0; ti < 4; ++ti)
#pragma unroll
      for (int tj = 0; tj < 4; ++tj)
        acc[ti][tj] = __builtin_amdgcn_mfma_f32_16x16x32_bf16(
            af[ti], bfv[tj], acc[ti][tj], 0, 0, 0);
  }

  // epilogue: C/D layout col=lane&15, row=(lane>>4)*4+reg (m89/m91 verified)
  const int r0 = (lane >> 4) * 4;
#pragma unroll
  for (int ti = 0; ti < 4; ++ti) {
#pragma unroll
    for (int r = 0; r < 4; ++r) {
      const int grow = bm + wr + ti * 16 + r0 + r;
#pragma unroll
      for (int tj = 0; tj < 4; ++tj) {
        const int gcol = bn + wc + tj * 16 + lm;
        const size_t idx = (size_t)grow * N + gcol;
        float v = acc[ti][tj][r] + bias[gcol];
        if (EPI == 1) v = 0.5f * v * (1.0f + erff(v * 0.70710678118654752f));
        if (EPI == 2) v += res[idx];
        if (OUTF) Cf[idx] = v;
        else      Cb[idx] = f2bf(v);
      }
    }
  }
}

// ---------------------------------------------------------------------------
// LayerNorm: fp32 in, bf16 out. One block per row (D=1024).
// ---------------------------------------------------------------------------
__global__ __launch_bounds__(256) void ln_kernel(
    const float* __restrict__ x, const float* __restrict__ g,
    const float* __restrict__ b, u16* __restrict__ o)
{
  const int row = blockIdx.x;
  const int t = threadIdx.x;
  float4 v = *(const float4*)(x + (size_t)row * D_MODEL + t * 4);
  float s  = v.x + v.y + v.z + v.w;
  float ss = v.x * v.x + v.y * v.y + v.z * v.z + v.w * v.w;
#pragma unroll
  for (int off = 32; off > 0; off >>= 1) {
    s  += __shfl_down(s, off);
    ss += __shfl_down(ss, off);
  }
  __shared__ float sm[4], ssm[4], stat[2];
  if ((t & 63) == 0) { sm[t >> 6] = s; ssm[t >> 6] = ss; }
  __syncthreads();
  if (t == 0) {
    float S = sm[0] + sm[1] + sm[2] + sm[3];
    float SS = ssm[0] + ssm[1] + ssm[2] + ssm[3];
    float mu = S * (1.0f / 1024.0f);
    float var = SS * (1.0f / 1024.0f) - mu * mu;
    stat[0] = mu;
    stat[1] = rsqrtf(fmaxf(var, 0.0f) + 1e-5f);
  }
  __syncthreads();
  const float mu = stat[0], rstd = stat[1];
  float4 gg = *(const float4*)(g + t * 4);
  float4 bb = *(const float4*)(b + t * 4);
  u16 o0 = f2bf((v.x - mu) * rstd * gg.x + bb.x);
  u16 o1 = f2bf((v.y - mu) * rstd * gg.y + bb.y);
  u16 o2 = f2bf((v.z - mu) * rstd * gg.z + bb.z);
  u16 o3 = f2bf((v.w - mu) * rstd * gg.w + bb.w);
  uint2 w;
  w.x = (u32)o0 | ((u32)o1 << 16);
  w.y = (u32)o2 | ((u32)o3 << 16);
  *(uint2*)(o + (size_t)row * D_MODEL + t * 4) = w;
}

// ---------------------------------------------------------------------------
// Banded attention (bf16 QKV in, bf16 AO out). Block = (bh, 64-row q-tile).
// Chunk 0 = global cols [0,16); then window [max(16,i0-128), min(S,i0+192)).
// Online softmax in fp32. Rows i<16 handled by attn_global_rows.
// qkv layout: [B*S][3072] = [q | k | v] per row.
// ---------------------------------------------------------------------------
__global__ __launch_bounds__(256) void attn_band(
    const u16* __restrict__ qkv, u16* __restrict__ out)
{
  const int t  = threadIdx.x;
  const int bh = blockIdx.y;
  const int b  = bh >> 4, h = bh & 15;
  const int i0 = blockIdx.x * 64;
  __shared__ __attribute__((aligned(16))) float Qs[64][68];
  __shared__ __attribute__((aligned(16))) float Ks[16][68];
  __shared__ __attribute__((aligned(16))) float Vs[16][68];
  const size_t bb = (size_t)b * S_LEN;

  { // stage Q (scaled by 1/sqrt(64))
    const int r = t >> 2, c0 = (t & 3) * 16;
    const u16* qr = qkv + (bb + i0 + r) * 3072 + h * 64 + c0;
    uint4 ra = *(const uint4*)qr;
    uint4 rb = *(const uint4*)(qr + 8);
    float* d = &Qs[r][c0];
    d[0] = bflo(ra.x) * 0.125f;  d[1] = bfhi(ra.x) * 0.125f;
    d[2] = bflo(ra.y) * 0.125f;  d[3] = bfhi(ra.y) * 0.125f;
    d[4] = bflo(ra.z) * 0.125f;  d[5] = bfhi(ra.z) * 0.125f;
    d[6] = bflo(ra.w) * 0.125f;  d[7] = bfhi(ra.w) * 0.125f;
    d[8] = bflo(rb.x) * 0.125f;  d[9] = bfhi(rb.x) * 0.125f;
    d[10] = bflo(rb.y) * 0.125f; d[11] = bfhi(rb.y) * 0.125f;
    d[12] = bflo(rb.z) * 0.125f; d[13] = bfhi(rb.z) * 0.125f;
    d[14] = bflo(rb.w) * 0.125f; d[15] = bfhi(rb.w) * 0.125f;
  }

  const int il = t >> 2;       // local q row 0..63
  const int jg = t & 3;        // j-group (4 keys) & d-slice selector
  const int iG = i0 + il;

  float mPrev = -1e30f, lSum = 0.f;
  float O[16];
#pragma unroll
  for (int d = 0; d < 16; ++d) O[d] = 0.f;

  const int lo = max(16, i0 - 128);
  const int hi = min(S_LEN, i0 + 64 + 128);
  const int nChunks = 1 + (hi - lo) / 16;

  for (int c = 0; c < nChunks; ++c) {
    const int j0 = (c == 0) ? 0 : lo + (c - 1) * 16;
    __syncthreads();  // protect Ks/Vs (and cover Q staging on c==0)
    { // stage K,V chunk [16][64]
      const int jr = t >> 4, d0 = (t & 15) * 4;
      const u16* kr = qkv + (bb + j0 + jr) * 3072 + 1024 + h * 64 + d0;
      uint2 kk = *(const uint2*)kr;
      uint2 vv = *(const uint2*)(kr + 1024);
      Ks[jr][d0]     = bflo(kk.x); Ks[jr][d0 + 1] = bfhi(kk.x);
      Ks[jr][d0 + 2] = bflo(kk.y); Ks[jr][d0 + 3] = bfhi(kk.y);
      Vs[jr][d0]     = bflo(vv.x); Vs[jr][d0 + 1] = bfhi(vv.x);
      Vs[jr][d0 + 2] = bflo(vv.y); Vs[jr][d0 + 3] = bfhi(vv.y);
    }
    __syncthreads();

    float sc[4] = {0.f, 0.f, 0.f, 0.f};
    const f32x4* q4 = (const f32x4*)&Qs[il][0];
    const f32x4* k0v = (const f32x4*)&Ks[jg * 4 + 0][0];
    const f32x4* k1v = (const f32x4*)&Ks[jg * 4 + 1][0];
    const f32x4* k2v = (const f32x4*)&Ks[jg * 4 + 2][0];
    const f32x4* k3v = (const f32x4*)&Ks[jg * 4 + 3][0];
#pragma unroll
    for (int dq = 0; dq < 16; ++dq) {
      f32x4 qv = q4[dq];
      f32x4 a0 = k0v[dq], a1 = k1v[dq], a2 = k2v[dq], a3 = k3v[dq];
      sc[0] += qv.x * a0.x + qv.y * a0.y + qv.z * a0.z + qv.w * a0.w;
      sc[1] += qv.x * a1.x + qv.y * a1.y + qv.z * a1.z + qv.w * a1.w;
      sc[2] += qv.x * a2.x + qv.y * a2.y + qv.z * a2.z + qv.w * a2.w;
      sc[3] += qv.x * a3.x + qv.y * a3.y + qv.z * a3.z + qv.w * a3.w;
    }
#pragma unroll
    for (int cc = 0; cc < 4; ++cc) {
      const int j = j0 + jg * 4 + cc;
      const bool ok = (j < 16) || (iG < 16) || (j >= iG - 128 && j <= iG + 128);
      if (!ok) sc[cc] = -1e30f;
    }
    float mc = fmaxf(fmaxf(sc[0], sc[1]), fmaxf(sc[2], sc[3]));
    mc = fmaxf(mc, __shfl_xor(mc, 1, 4));
    mc = fmaxf(mc, __shfl_xor(mc, 2, 4));
    const float mNew = fmaxf(mPrev, mc);
    const float alpha = __expf(mPrev - mNew);
    float p[4], ps = 0.f;
#pragma unroll
    for (int cc = 0; cc < 4; ++cc) { p[cc] = __expf(sc[cc] - mNew); ps += p[cc]; }
    ps += __shfl_xor(ps, 1, 4);
    ps += __shfl_xor(ps, 2, 4);
    lSum = lSum * alpha + ps;
    mPrev = mNew;
#pragma unroll
    for (int d = 0; d < 16; ++d) O[d] *= alpha;

    const int dbase = jg * 4;  // thread's 16-float d-slice (f32x4 units)
#pragma unroll
    for (int jj = 0; jj < 16; ++jj) {
      const float pv = __shfl(p[jj & 3], jj >> 2, 4);
      const f32x4* v4 = (const f32x4*)&Vs[jj][0];
#pragma unroll
      for (int q = 0; q < 4; ++q) {
        f32x4 vv = v4[dbase + q];
        O[q * 4 + 0] += pv * vv.x;
        O[q * 4 + 1] += pv * vv.y;
        O[q * 4 + 2] += pv * vv.z;
        O[q * 4 + 3] += pv * vv.w;
      }
    }
  }

  if (iG >= 16) {
    const float inv = 1.0f / lSum;
    u16* orow = out + (bb + iG) * 1024 + h * 64 + jg * 16;
    u32 w[8];
#pragma unroll
    for (int q = 0; q < 8; ++q)
      w[q] = (u32)f2bf(O[2 * q] * inv) | ((u32)f2bf(O[2 * q + 1] * inv) << 16);
    uint4 s0; s0.x = w[0]; s0.y = w[1]; s0.z = w[2]; s0.w = w[3];
    uint4 s1; s1.x = w[4]; s1.y = w[5]; s1.z = w[6]; s1.w = w[7];
    *(uint4*)orow = s0;
    *(uint4*)(orow + 8) = s1;
  }
}

// ---------------------------------------------------------------------------
// Global rows (i < 16): full attention over all 2048 keys. Block per (b,h,i).
// ---------------------------------------------------------------------------
__global__ __launch_bounds__(256) void attn_global_rows(
    const u16* __restrict__ qkv, u16* __restrict__ out)
{
  const int t  = threadIdx.x;
  const int gi = blockIdx.x;          // 512 = B*H*16
  const int i  = gi & 15;
  const int bh = gi >> 4;
  const int b  = bh >> 4, h = bh & 15;
  __shared__ float Ss[2048];
  __shared__ float qs[64];
  __shared__ float red[4];
  __shared__ float ML[2];
  __shared__ float Opart[4][64];
  const size_t bb = (size_t)b * S_LEN;

  if (t < 64) qs[t] = bf2f(qkv[(bb + i) * 3072 + h * 64 + t]) * 0.125f;
  __syncthreads();

  for (int c = 0; c < 8; ++c) {
    const u16* kr = qkv + (bb + c * 256 + t) * 3072 + 1024 + h * 64;
    float acc = 0.f;
#pragma unroll
    for (int q = 0; q < 8; ++q) {
      uint4 rr = *(const uint4*)(kr + q * 8);
      acc += qs[q * 8 + 0] * bflo(rr.x) + qs[q * 8 + 1] * bfhi(rr.x)
           + qs[q * 8 + 2] * bflo(rr.y) + qs[q * 8 + 3] * bfhi(rr.y)
           + qs[q * 8 + 4] * bflo(rr.z) + qs[q * 8 + 5] * bfhi(rr.z)
           + qs[q * 8 + 6] * bflo(rr.w) + qs[q * 8 + 7] * bfhi(rr.w);
    }
    Ss[c * 256 + t] = acc;
  }
  __syncthreads();

  float m = -1e30f;
#pragma unroll
  for (int c = 0; c < 8; ++c) m = fmaxf(m, Ss[c * 256 + t]);
#pragma unroll
  for (int off = 32; off > 0; off >>= 1) m = fmaxf(m, __shfl_xor(m, off));
  if ((t & 63) == 0) red[t >> 6] = m;
  __syncthreads();
  if (t == 0) ML[0] = fmaxf(fmaxf(red[0], red[1]), fmaxf(red[2], red[3]));
  __syncthreads();
  const float M = ML[0];
  float ls = 0.f;
#pragma unroll
  for (int c = 0; c < 8; ++c) {
    float p = __expf(Ss[c * 256 + t] - M);
    Ss[c * 256 + t] = p;
    ls += p;
  }
#pragma unroll
  for (int off = 32; off > 0; off >>= 1) ls += __shfl_xor(ls, off);
  __syncthreads();
  if ((t & 63) == 0) red[t >> 6] = ls;
  __syncthreads();
  if (t == 0) ML[1] = red[0] + red[1] + red[2] + red[3];
  __syncthreads();
  const float L = ML[1];

  const int d  = t & 63;
  const int qd = t >> 6;
  float oacc = 0.f;
  for (int c = 0; c < 8; ++c) {
#pragma unroll 8
    for (int jl = 0; jl < 64; ++jl) {
      const int j = c * 256 + qd * 64 + jl;
      oacc += Ss[j] * bf2f(qkv[(bb + j) * 3072 + 2048 + h * 64 + d]);
    }
  }
  Opart[qd][d] = oacc;
  __syncthreads();
  if (t < 64) {
    float o = (Opart[0][t] + Opart[1][t] + Opart[2][t] + Opart[3][t]) / L;
    out[(bb + i) * 1024 + h * 64 + t] = f2bf(o);
  }
}

// ---------------------------------------------------------------------------
// Transpose + fp32->bf16 convert: out[Cc][R] bf16, out[c][r] = in[r][c] (fp32).
// 64x64 tiles via LDS.
// ---------------------------------------------------------------------------
__global__ __launch_bounds__(256) void transpose_cvt(
    const float* __restrict__ in, u16* __restrict__ outp, int R, int Cc)
{
  __shared__ u16 tile[64][65];
  const int t = threadIdx.x;
  const int tr = blockIdx.y * 64, tc = blockIdx.x * 64;
  const int lr = t >> 2, lc0 = (t & 3) * 16;
  const float* src = in + (size_t)(tr + lr) * Cc + tc + lc0;
  float4 a0 = *(const float4*)(src);
  float4 a1 = *(const float4*)(src + 4);
  float4 a2 = *(const float4*)(src + 8);
  float4 a3 = *(const float4*)(src + 12);
  const float vals[16] = {a0.x, a0.y, a0.z, a0.w, a1.x, a1.y, a1.z, a1.w,
                          a2.x, a2.y, a2.z, a2.w, a3.x, a3.y, a3.z, a3.w};
#pragma unroll
  for (int q = 0; q < 16; ++q) tile[lr][lc0 + q] = f2bf(vals[q]);
  __syncthreads();
  u16* dst = outp + (size_t)(tc + lr) * R + tr + lc0;
  u32 w[8];
#pragma unroll
  for (int q = 0; q < 8; ++q)
    w[q] = (u32)tile[lc0 + 2 * q][lr] | ((u32)tile[lc0 + 2 * q + 1][lr] << 16);
  uint4 s0; s0.x = w[0]; s0.y = w[1]; s0.z = w[2]; s0.w = w[3];
  uint4 s1; s1.x = w[4]; s1.y = w[5]; s1.z = w[6]; s1.w = w[7];
  *(uint4*)dst = s0;
  *(uint4*)(dst + 8) = s1;
}

__global__ __launch_bounds__(256) void concat3(
    const float* __restrict__ a, const float* __restrict__ b,
    const float* __restrict__ c, float* __restrict__ o)
{
  const int i = blockIdx.x * 256 + threadIdx.x;  // grid 12 -> 3072
  if (i < 1024) o[i] = a[i];
  else if (i < 2048) o[i] = b[i - 1024];
  else o[i] = c[i - 2048];
}

// ---------------------------------------------------------------------------
// workspace layout (bytes) — ~64 MB. Residual stream X1 + final out in d_out
// (fp32). H (bf16 [4096][4096]) aliases QKV+AO (dead by then).
// ---------------------------------------------------------------------------
static const size_t OFF_WQKVT = 0;                                   // bf16 [3072][1024]
static const size_t OFF_WOT   = OFF_WQKVT + (size_t)3072 * 1024 * 2; // bf16 [1024][1024]
static const size_t OFF_W1T   = OFF_WOT   + (size_t)1024 * 1024 * 2; // bf16 [4096][1024]
static const size_t OFF_W2T   = OFF_W1T   + (size_t)4096 * 1024 * 2; // bf16 [1024][4096]
static const size_t OFF_BQKV  = OFF_W2T   + (size_t)1024 * 4096 * 2; // fp32 [3072]
static const size_t OFF_XN    = OFF_BQKV  + 16384;                   // bf16 [4096][1024]
static const size_t OFF_QKV   = OFF_XN    + (size_t)4096 * 1024 * 2; // bf16 [4096][3072]
static const size_t OFF_AO    = OFF_QKV   + (size_t)4096 * 3072 * 2; // bf16 [4096][1024]
static const size_t OFF_H     = OFF_QKV;  // bf16 [4096][4096], aliases QKV+AO

extern "C" void kernel_launch(void* const* d_in, const int* in_sizes, int n_in,
                              void* d_out, int out_size, void* d_ws, size_t ws_size,
                              hipStream_t stream)
{
  const float* x   = (const float*)d_in[0];
  const float* Wq  = (const float*)d_in[1];
  const float* bq  = (const float*)d_in[2];
  const float* Wk  = (const float*)d_in[3];
  const float* bk  = (const float*)d_in[4];
  const float* Wv  = (const float*)d_in[5];
  const float* bv  = (const float*)d_in[6];
  const float* Wo  = (const float*)d_in[7];
  const float* bo  = (const float*)d_in[8];
  const float* g1  = (const float*)d_in[9];
  const float* be1 = (const float*)d_in[10];
  const float* W1  = (const float*)d_in[11];
  const float* b1  = (const float*)d_in[12];
  const float* W2  = (const float*)d_in[13];
  const float* b2  = (const float*)d_in[14];
  const float* g2  = (const float*)d_in[15];
  const float* be2 = (const float*)d_in[16];
  float* outf = (float*)d_out;
  char* ws = (char*)d_ws;

  u16*   WQKVT = (u16*)(ws + OFF_WQKVT);
  u16*   WOT   = (u16*)(ws + OFF_WOT);
  u16*   W1T   = (u16*)(ws + OFF_W1T);
  u16*   W2T   = (u16*)(ws + OFF_W2T);
  float* BQKV  = (float*)(ws + OFF_BQKV);
  u16*   XN    = (u16*)(ws + OFF_XN);
  u16*   QKV   = (u16*)(ws + OFF_QKV);
  u16*   AO    = (u16*)(ws + OFF_AO);
  u16*   Hbuf  = (u16*)(ws + OFF_H);
  float* X1    = outf;  // fp32 residual stream #2 lives in d_out

  const dim3 blk(256);
  // weight transposes+convert (grid = (Cc/64, R/64))
  transpose_cvt<<<dim3(16, 16), blk, 0, stream>>>(Wq, WQKVT,               1024, 1024);
  transpose_cvt<<<dim3(16, 16), blk, 0, stream>>>(Wk, WQKVT + 1024 * 1024, 1024, 1024);
  transpose_cvt<<<dim3(16, 16), blk, 0, stream>>>(Wv, WQKVT + 2048 * 1024, 1024, 1024);
  transpose_cvt<<<dim3(16, 16), blk, 0, stream>>>(Wo, WOT,                 1024, 1024);
  transpose_cvt<<<dim3(64, 16), blk, 0, stream>>>(W1, W1T,                 1024, 4096);
  transpose_cvt<<<dim3(16, 64), blk, 0, stream>>>(W2, W2T,                 4096, 1024);
  concat3<<<dim3(12), blk, 0, stream>>>(bq, bk, bv, BQKV);

  // attention sublayer
  ln_kernel<<<dim3(ROWS), blk, 0, stream>>>(x, g1, be1, XN);
  gemm_bt<0, 0><<<dim3(24, 32), blk, 0, stream>>>(XN, WQKVT, BQKV, nullptr,
                                                  QKV, nullptr, ROWS, 3072, 1024);
  attn_band<<<dim3(32, 32), blk, 0, stream>>>(QKV, AO);
  attn_global_rows<<<dim3(512), blk, 0, stream>>>(QKV, AO);
  gemm_bt<2, 1><<<dim3(8, 32), blk, 0, stream>>>(AO, WOT, bo, x,
                                                 nullptr, X1, ROWS, 1024, 1024);

  // FFN sublayer
  ln_kernel<<<dim3(ROWS), blk, 0, stream>>>(X1, g2, be2, XN);
  gemm_bt<1, 0><<<dim3(32, 32), blk, 0, stream>>>(XN, W1T, b1, nullptr,
                                                  Hbuf, nullptr, ROWS, 4096, 1024);
  gemm_bt<2, 1><<<dim3(8, 32), blk, 0, stream>>>(Hbuf, W2T, b2, X1,
                                                 nullptr, outf, ROWS, 1024, 4096);
}

// Round 4
// 523.355 us; speedup vs baseline: 1.1793x; 1.1793x over previous
//
#include <hip/hip_runtime.h>
#include <stdint.h>

// ---------------------------------------------------------------------------
// EncoderBlock: pre-norm transformer block, MI355X (gfx950).
// External dtype: FP32 (per reference). Internal: bf16 MFMA, fp32 accum,
// fp32 residual stream.
// B=2 S=2048 D=1024 H=16 DK=64 DFF=4096 WINDOW=128 GLOBAL=16
// ---------------------------------------------------------------------------

typedef unsigned short u16;
typedef unsigned int   u32;
typedef __attribute__((ext_vector_type(8))) short  short8;  // 8 bf16 (4 VGPRs)
typedef __attribute__((ext_vector_type(4))) float  f32x4;

#define S_LEN   2048
#define D_MODEL 1024
#define ROWS    4096   // B*S

__device__ __forceinline__ float bf2f(u16 u) {
  union { u32 i; float f; } v; v.i = ((u32)u) << 16; return v.f;
}
__device__ __forceinline__ float bflo(u32 u) {
  union { u32 i; float f; } v; v.i = u << 16; return v.f;
}
__device__ __forceinline__ float bfhi(u32 u) {
  union { u32 i; float f; } v; v.i = u & 0xffff0000u; return v.f;
}
__device__ __forceinline__ u16 f2bf(float f) {
  union { float f; u32 i; } v; v.f = f;
  u32 r = v.i + 0x7fffu + ((v.i >> 16) & 1u);
  return (u16)(r >> 16);
}

// Direct global->LDS copy, 16B/lane (m97: +69% GEMM). LDS dest is
// wave-uniform base; data lands at base + lane*16. Low 32 bits of a generic
// LDS pointer are the LDS offset (shared aperture is 2^32-aligned), so the
// inttoptr truncation is correct.
__device__ __forceinline__ void gld_lds16(const u16* g, u16* l) {
  __attribute__((address_space(3))) u32* lp =
      reinterpret_cast<__attribute__((address_space(3))) u32*>(
          reinterpret_cast<uintptr_t>(l));
  const __attribute__((address_space(1))) u32* gp =
      reinterpret_cast<const __attribute__((address_space(1))) u32*>(
          reinterpret_cast<uintptr_t>(g));
  __builtin_amdgcn_global_load_lds(gp, lp, 16, 0, 0);
}

// ---------------------------------------------------------------------------
// GEMM: C[M,N] = A[M,K] @ B[K,N] (+bias, opt gelu/residual). A, Bt are bf16
// (Bt = B^T, K contiguous). bias/res fp32. OUTF: 0 = bf16 out, 1 = fp32 out.
// m97 structure: 128x128 tile, BK=32, 4 waves x (4x4) mfma_f32_16x16x32_bf16,
// global_load_lds width-16 staging.
// EPI: 0=bias, 1=bias+gelu, 2=bias+residual.
// ---------------------------------------------------------------------------
template <int EPI, int OUTF>
__global__ __launch_bounds__(256) void gemm_bt(
    const u16* __restrict__ A, const u16* __restrict__ Bt,
    const float* __restrict__ bias, const float* res,
    u16* Cb, float* Cf, int M, int N, int K)
{
  __shared__ __attribute__((aligned(16))) u16 As[128 * 32];
  __shared__ __attribute__((aligned(16))) u16 Bs[128 * 32];
  const int tid  = threadIdx.x;
  const int wave = tid >> 6;
  const int lane = tid & 63;
  const int bm = blockIdx.y * 128;
  const int bn = blockIdx.x * 128;
  const int wr = (wave >> 1) * 64;   // wave row offset in tile
  const int wc = (wave & 1) * 64;    // wave col offset in tile
  const int lm = lane & 15;
  const int kq = lane >> 4;          // 0..3 (k-quad)

  f32x4 acc[4][4];
#pragma unroll
  for (int i = 0; i < 4; ++i)
#pragma unroll
    for (int j = 0; j < 4; ++j) acc[i][j] = (f32x4){0.f, 0.f, 0.f, 0.f};

  // staging: wave w covers rows [16w,16w+16) and [64+16w,...); lane ->
  // row 16w + (lane>>2), k-chunk (lane&3)*8 — byte offset = lane*16 from the
  // wave-uniform LDS base (matches global_load_lds lane scatter).
  const int srow = wave * 16 + (lane >> 2);
  const int skc  = (lane & 3) * 8;
  const u16* gA = A  + (size_t)(bm + srow) * K + skc;
  const u16* gB = Bt + (size_t)(bn + srow) * K + skc;
  u16* lA = &As[(wave * 16) * 32];
  u16* lB = &Bs[(wave * 16) * 32];

  for (int k0 = 0; k0 < K; k0 += 32) {
    gld_lds16(gA + k0, lA);
    gld_lds16(gA + (size_t)64 * K + k0, lA + 64 * 32);
    gld_lds16(gB + k0, lB);
    gld_lds16(gB + (size_t)64 * K + k0, lB + 64 * 32);
    __syncthreads();  // drains vmcnt before barrier (compiler-emitted)

    short8 af[4], bfv[4];
#pragma unroll
    for (int ti = 0; ti < 4; ++ti)
      af[ti] = *(const short8*)&As[(wr + ti * 16 + lm) * 32 + kq * 8];
#pragma unroll
    for (int tj = 0; tj < 4; ++tj)
      bfv[tj] = *(const short8*)&Bs[(wc + tj * 16 + lm) * 32 + kq * 8];
#pragma unroll
    for (int ti = 0; ti < 4; ++ti)
#pragma unroll
      for (int tj = 0; tj < 4; ++tj)
        acc[ti][tj] = __builtin_amdgcn_mfma_f32_16x16x32_bf16(
            af[ti], bfv[tj], acc[ti][tj], 0, 0, 0);
    __syncthreads();
  }

  // epilogue: C/D layout col=lane&15, row=(lane>>4)*4+reg (m89/m91 verified)
  const int r0 = (lane >> 4) * 4;
#pragma unroll
  for (int ti = 0; ti < 4; ++ti) {
#pragma unroll
    for (int r = 0; r < 4; ++r) {
      const int grow = bm + wr + ti * 16 + r0 + r;
#pragma unroll
      for (int tj = 0; tj < 4; ++tj) {
        const int gcol = bn + wc + tj * 16 + lm;
        const size_t idx = (size_t)grow * N + gcol;
        float v = acc[ti][tj][r] + bias[gcol];
        if (EPI == 1) v = 0.5f * v * (1.0f + erff(v * 0.70710678118654752f));
        if (EPI == 2) v += res[idx];
        if (OUTF) Cf[idx] = v;
        else      Cb[idx] = f2bf(v);
      }
    }
  }
}

// ---------------------------------------------------------------------------
// LayerNorm: fp32 in, bf16 out. One block per row (D=1024).
// ---------------------------------------------------------------------------
__global__ __launch_bounds__(256) void ln_kernel(
    const float* __restrict__ x, const float* __restrict__ g,
    const float* __restrict__ b, u16* __restrict__ o)
{
  const int row = blockIdx.x;
  const int t = threadIdx.x;
  float4 v = *(const float4*)(x + (size_t)row * D_MODEL + t * 4);
  float s  = v.x + v.y + v.z + v.w;
  float ss = v.x * v.x + v.y * v.y + v.z * v.z + v.w * v.w;
#pragma unroll
  for (int off = 32; off > 0; off >>= 1) {
    s  += __shfl_down(s, off);
    ss += __shfl_down(ss, off);
  }
  __shared__ float sm[4], ssm[4], stat[2];
  if ((t & 63) == 0) { sm[t >> 6] = s; ssm[t >> 6] = ss; }
  __syncthreads();
  if (t == 0) {
    float S = sm[0] + sm[1] + sm[2] + sm[3];
    float SS = ssm[0] + ssm[1] + ssm[2] + ssm[3];
    float mu = S * (1.0f / 1024.0f);
    float var = SS * (1.0f / 1024.0f) - mu * mu;
    stat[0] = mu;
    stat[1] = rsqrtf(fmaxf(var, 0.0f) + 1e-5f);
  }
  __syncthreads();
  const float mu = stat[0], rstd = stat[1];
  float4 gg = *(const float4*)(g + t * 4);
  float4 bb = *(const float4*)(b + t * 4);
  u16 o0 = f2bf((v.x - mu) * rstd * gg.x + bb.x);
  u16 o1 = f2bf((v.y - mu) * rstd * gg.y + bb.y);
  u16 o2 = f2bf((v.z - mu) * rstd * gg.z + bb.z);
  u16 o3 = f2bf((v.w - mu) * rstd * gg.w + bb.w);
  uint2 w;
  w.x = (u32)o0 | ((u32)o1 << 16);
  w.y = (u32)o2 | ((u32)o3 << 16);
  *(uint2*)(o + (size_t)row * D_MODEL + t * 4) = w;
}

// ---------------------------------------------------------------------------
// Banded attention, MFMA flash style. Block = (bh, 64 q-rows); 4 waves, each
// wave owns 16 q-rows. K-chunks of 32 keys: chunk 0 = keys [0,32) (covers
// global cols, band-masked), then window [max(32,i0-128), min(S,i0+192)).
// QK^T: 4x mfma_16x16x32 -> scores in C-layout (col=key, row=quad*4+reg).
// Online softmax per C-row in registers (shfl_xor width 16 = within quad).
// P round-trips LDS (bf16) to A-layout; PV: 4x mfma with V staged transposed
// (Vt[d][key]) so the B-operand reads are contiguous. Layout mappings per
// m89/m91 (C/D) and m120 (A: A[m=lane&15][k=quad*8+j]).
// Rows i<16 are handled by attn_global_rows (tile0/wave0 skips its store).
// qkv layout: [B*S][3072] = [q | k | v] per row.
// ---------------------------------------------------------------------------
__global__ __launch_bounds__(256) void attn_band(
    const u16* __restrict__ qkv, u16* __restrict__ out)
{
  const int t    = threadIdx.x;
  const int w    = t >> 6;
  const int lane = t & 63;
  const int m    = lane & 15;
  const int quad = lane >> 4;
  const int bh   = blockIdx.y;
  const int b    = bh >> 4, h = bh & 15;
  const int i0   = blockIdx.x * 64;
  const size_t bb = (size_t)b * S_LEN;

  // padded strides (u16): Ks 72 (144B=9x16B), Vt/Ps 40 (80B=5x16B) ->
  // 16B-aligned b128 reads, 2-way bank aliasing only (free, m136).
  __shared__ __attribute__((aligned(16))) u16 Ks[32 * 72];
  __shared__ __attribute__((aligned(16))) u16 Vt[64 * 40];
  __shared__ __attribute__((aligned(16))) u16 Ps[4][16 * 40];

  // Q fragments (A-layout), loaded once: row i0+16w+m, d = {quad*8, 32+quad*8}
  const u16* qrow = qkv + (bb + i0 + 16 * w + m) * 3072 + h * 64;
  const short8 aq0 = *(const short8*)(qrow + quad * 8);
  const short8 aq1 = *(const short8*)(qrow + 32 + quad * 8);

  f32x4 Ov[4];
#pragma unroll
  for (int td = 0; td < 4; ++td) Ov[td] = (f32x4){0.f, 0.f, 0.f, 0.f};
  float mP[4] = {-1e30f, -1e30f, -1e30f, -1e30f};
  float lS[4] = {0.f, 0.f, 0.f, 0.f};

  const int iB = i0 + 16 * w + quad * 4;  // q-row base for this lane's regs

  const int lo = max(32, i0 - 128);
  const int hi = min(S_LEN, i0 + 192);
  const int nChunks = 1 + (hi - lo) / 32;

  const int skr = t >> 3;          // staging: key row 0..31
  const int skc = (t & 7) * 8;     // staging: d offset

  for (int c = 0; c < nChunks; ++c) {
    const int j0 = (c == 0) ? 0 : lo + (c - 1) * 32;
    __syncthreads();  // protect Ks/Vt from previous chunk's readers
    {
      const u16* src = qkv + (bb + j0 + skr) * 3072 + 1024 + h * 64 + skc;
      uint4 kk = *(const uint4*)src;
      uint4 vv = *(const uint4*)(src + 1024);
      *(uint4*)&Ks[skr * 72 + skc] = kk;
      const u16 vs[8] = {
        (u16)(vv.x & 0xffffu), (u16)(vv.x >> 16),
        (u16)(vv.y & 0xffffu), (u16)(vv.y >> 16),
        (u16)(vv.z & 0xffffu), (u16)(vv.z >> 16),
        (u16)(vv.w & 0xffffu), (u16)(vv.w >> 16)};
#pragma unroll
      for (int i = 0; i < 8; ++i) Vt[(skc + i) * 40 + skr] = vs[i];
    }
    __syncthreads();

    // QK^T for 2 key-tiles (B-operand = Ks rows, contiguous in d)
    const short8 b00 = *(const short8*)&Ks[m * 72 + quad * 8];
    const short8 b01 = *(const short8*)&Ks[m * 72 + 32 + quad * 8];
    const short8 b10 = *(const short8*)&Ks[(16 + m) * 72 + quad * 8];
    const short8 b11 = *(const short8*)&Ks[(16 + m) * 72 + 32 + quad * 8];
    f32x4 s0 = (f32x4){0.f, 0.f, 0.f, 0.f};
    f32x4 s1 = (f32x4){0.f, 0.f, 0.f, 0.f};
    s0 = __builtin_amdgcn_mfma_f32_16x16x32_bf16(aq0, b00, s0, 0, 0, 0);
    s0 = __builtin_amdgcn_mfma_f32_16x16x32_bf16(aq1, b01, s0, 0, 0, 0);
    s1 = __builtin_amdgcn_mfma_f32_16x16x32_bf16(aq0, b10, s1, 0, 0, 0);
    s1 = __builtin_amdgcn_mfma_f32_16x16x32_bf16(aq1, b11, s1, 0, 0, 0);

    // scale + band mask (j<16 = global col; |i-j|<=128 = window)
    const int jA = j0 + m, jB = j0 + 16 + m;
#pragma unroll
    for (int r = 0; r < 4; ++r) {
      const int iG = iB + r;
      const int da = iG - jA, db = iG - jB;
      s0[r] = ((jA < 16) || (da >= -128 && da <= 128)) ? s0[r] * 0.125f : -1e30f;
      s1[r] = ((jB < 16) || (db >= -128 && db <= 128)) ? s1[r] * 0.125f : -1e30f;
    }

    // online softmax per row r (reduce across the 16 lanes of the quad)
    float al[4];
#pragma unroll
    for (int r = 0; r < 4; ++r) {
      float mx = fmaxf(s0[r], s1[r]);
      mx = fmaxf(mx, __shfl_xor(mx, 1, 16));
      mx = fmaxf(mx, __shfl_xor(mx, 2, 16));
      mx = fmaxf(mx, __shfl_xor(mx, 4, 16));
      mx = fmaxf(mx, __shfl_xor(mx, 8, 16));
      const float mn = fmaxf(mP[r], mx);
      al[r] = __expf(mP[r] - mn);
      mP[r] = mn;
      const float p0 = __expf(s0[r] - mn);
      const float p1 = __expf(s1[r] - mn);
      float ps = p0 + p1;
      ps += __shfl_xor(ps, 1, 16);
      ps += __shfl_xor(ps, 2, 16);
      ps += __shfl_xor(ps, 4, 16);
      ps += __shfl_xor(ps, 8, 16);
      lS[r] = lS[r] * al[r] + ps;
      Ps[w][(quad * 4 + r) * 40 + m]      = f2bf(p0);
      Ps[w][(quad * 4 + r) * 40 + 16 + m] = f2bf(p1);
    }
#pragma unroll
    for (int td = 0; td < 4; ++td)
#pragma unroll
      for (int r = 0; r < 4; ++r) Ov[td][r] *= al[r];

    // P in A-layout (wave-internal LDS round trip; no barrier needed) + PV
    const short8 pa = *(const short8*)&Ps[w][m * 40 + quad * 8];
#pragma unroll
    for (int td = 0; td < 4; ++td) {
      const short8 bv = *(const short8*)&Vt[(td * 16 + m) * 40 + quad * 8];
      Ov[td] = __builtin_amdgcn_mfma_f32_16x16x32_bf16(pa, bv, Ov[td], 0, 0, 0);
    }
  }

  if (i0 + 16 * w >= 16) {  // wave-uniform; rows <16 stored by attn_global_rows
    float inv[4];
#pragma unroll
    for (int r = 0; r < 4; ++r) inv[r] = 1.0f / lS[r];
#pragma unroll
    for (int td = 0; td < 4; ++td)
#pragma unroll
      for (int r = 0; r < 4; ++r)
        out[(bb + iB + r) * 1024 + h * 64 + td * 16 + m] =
            f2bf(Ov[td][r] * inv[r]);
  }
}

// ---------------------------------------------------------------------------
// Global rows (i < 16): full attention over all 2048 keys. Block per (b,h,i).
// ---------------------------------------------------------------------------
__global__ __launch_bounds__(256) void attn_global_rows(
    const u16* __restrict__ qkv, u16* __restrict__ out)
{
  const int t  = threadIdx.x;
  const int gi = blockIdx.x;          // 512 = B*H*16
  const int i  = gi & 15;
  const int bh = gi >> 4;
  const int b  = bh >> 4, h = bh & 15;
  __shared__ float Ss[2048];
  __shared__ float qs[64];
  __shared__ float red[4];
  __shared__ float ML[2];
  __shared__ float Opart[4][64];
  const size_t bb = (size_t)b * S_LEN;

  if (t < 64) qs[t] = bf2f(qkv[(bb + i) * 3072 + h * 64 + t]) * 0.125f;
  __syncthreads();

  for (int c = 0; c < 8; ++c) {
    const u16* kr = qkv + (bb + c * 256 + t) * 3072 + 1024 + h * 64;
    float acc = 0.f;
#pragma unroll
    for (int q = 0; q < 8; ++q) {
      uint4 rr = *(const uint4*)(kr + q * 8);
      acc += qs[q * 8 + 0] * bflo(rr.x) + qs[q * 8 + 1] * bfhi(rr.x)
           + qs[q * 8 + 2] * bflo(rr.y) + qs[q * 8 + 3] * bfhi(rr.y)
           + qs[q * 8 + 4] * bflo(rr.z) + qs[q * 8 + 5] * bfhi(rr.z)
           + qs[q * 8 + 6] * bflo(rr.w) + qs[q * 8 + 7] * bfhi(rr.w);
    }
    Ss[c * 256 + t] = acc;
  }
  __syncthreads();

  float m = -1e30f;
#pragma unroll
  for (int c = 0; c < 8; ++c) m = fmaxf(m, Ss[c * 256 + t]);
#pragma unroll
  for (int off = 32; off > 0; off >>= 1) m = fmaxf(m, __shfl_xor(m, off));
  if ((t & 63) == 0) red[t >> 6] = m;
  __syncthreads();
  if (t == 0) ML[0] = fmaxf(fmaxf(red[0], red[1]), fmaxf(red[2], red[3]));
  __syncthreads();
  const float M = ML[0];
  float ls = 0.f;
#pragma unroll
  for (int c = 0; c < 8; ++c) {
    float p = __expf(Ss[c * 256 + t] - M);
    Ss[c * 256 + t] = p;
    ls += p;
  }
#pragma unroll
  for (int off = 32; off > 0; off >>= 1) ls += __shfl_xor(ls, off);
  __syncthreads();
  if ((t & 63) == 0) red[t >> 6] = ls;
  __syncthreads();
  if (t == 0) ML[1] = red[0] + red[1] + red[2] + red[3];
  __syncthreads();
  const float L = ML[1];

  const int d  = t & 63;
  const int qd = t >> 6;
  float oacc = 0.f;
  for (int c = 0; c < 8; ++c) {
#pragma unroll 8
    for (int jl = 0; jl < 64; ++jl) {
      const int j = c * 256 + qd * 64 + jl;
      oacc += Ss[j] * bf2f(qkv[(bb + j) * 3072 + 2048 + h * 64 + d]);
    }
  }
  Opart[qd][d] = oacc;
  __syncthreads();
  if (t < 64) {
    float o = (Opart[0][t] + Opart[1][t] + Opart[2][t] + Opart[3][t]) / L;
    out[(bb + i) * 1024 + h * 64 + t] = f2bf(o);
  }
}

// ---------------------------------------------------------------------------
// Transpose + fp32->bf16 convert: out[Cc][R] bf16, out[c][r] = in[r][c] (fp32).
// 64x64 tiles via LDS.
// ---------------------------------------------------------------------------
__global__ __launch_bounds__(256) void transpose_cvt(
    const float* __restrict__ in, u16* __restrict__ outp, int R, int Cc)
{
  __shared__ u16 tile[64][65];
  const int t = threadIdx.x;
  const int tr = blockIdx.y * 64, tc = blockIdx.x * 64;
  const int lr = t >> 2, lc0 = (t & 3) * 16;
  const float* src = in + (size_t)(tr + lr) * Cc + tc + lc0;
  float4 a0 = *(const float4*)(src);
  float4 a1 = *(const float4*)(src + 4);
  float4 a2 = *(const float4*)(src + 8);
  float4 a3 = *(const float4*)(src + 12);
  const float vals[16] = {a0.x, a0.y, a0.z, a0.w, a1.x, a1.y, a1.z, a1.w,
                          a2.x, a2.y, a2.z, a2.w, a3.x, a3.y, a3.z, a3.w};
#pragma unroll
  for (int q = 0; q < 16; ++q) tile[lr][lc0 + q] = f2bf(vals[q]);
  __syncthreads();
  u16* dst = outp + (size_t)(tc + lr) * R + tr + lc0;
  u32 w[8];
#pragma unroll
  for (int q = 0; q < 8; ++q)
    w[q] = (u32)tile[lc0 + 2 * q][lr] | ((u32)tile[lc0 + 2 * q + 1][lr] << 16);
  uint4 s0; s0.x = w[0]; s0.y = w[1]; s0.z = w[2]; s0.w = w[3];
  uint4 s1; s1.x = w[4]; s1.y = w[5]; s1.z = w[6]; s1.w = w[7];
  *(uint4*)dst = s0;
  *(uint4*)(dst + 8) = s1;
}

__global__ __launch_bounds__(256) void concat3(
    const float* __restrict__ a, const float* __restrict__ b,
    const float* __restrict__ c, float* __restrict__ o)
{
  const int i = blockIdx.x * 256 + threadIdx.x;  // grid 12 -> 3072
  if (i < 1024) o[i] = a[i];
  else if (i < 2048) o[i] = b[i - 1024];
  else o[i] = c[i - 2048];
}

// ---------------------------------------------------------------------------
// workspace layout (bytes) — ~64 MB. Residual stream X1 + final out in d_out
// (fp32). H (bf16 [4096][4096]) aliases QKV+AO (dead by then).
// ---------------------------------------------------------------------------
static const size_t OFF_WQKVT = 0;                                   // bf16 [3072][1024]
static const size_t OFF_WOT   = OFF_WQKVT + (size_t)3072 * 1024 * 2; // bf16 [1024][1024]
static const size_t OFF_W1T   = OFF_WOT   + (size_t)1024 * 1024 * 2; // bf16 [4096][1024]
static const size_t OFF_W2T   = OFF_W1T   + (size_t)4096 * 1024 * 2; // bf16 [1024][4096]
static const size_t OFF_BQKV  = OFF_W2T   + (size_t)1024 * 4096 * 2; // fp32 [3072]
static const size_t OFF_XN    = OFF_BQKV  + 16384;                   // bf16 [4096][1024]
static const size_t OFF_QKV   = OFF_XN    + (size_t)4096 * 1024 * 2; // bf16 [4096][3072]
static const size_t OFF_AO    = OFF_QKV   + (size_t)4096 * 3072 * 2; // bf16 [4096][1024]
static const size_t OFF_H     = OFF_QKV;  // bf16 [4096][4096], aliases QKV+AO

extern "C" void kernel_launch(void* const* d_in, const int* in_sizes, int n_in,
                              void* d_out, int out_size, void* d_ws, size_t ws_size,
                              hipStream_t stream)
{
  const float* x   = (const float*)d_in[0];
  const float* Wq  = (const float*)d_in[1];
  const float* bq  = (const float*)d_in[2];
  const float* Wk  = (const float*)d_in[3];
  const float* bk  = (const float*)d_in[4];
  const float* Wv  = (const float*)d_in[5];
  const float* bv  = (const float*)d_in[6];
  const float* Wo  = (const float*)d_in[7];
  const float* bo  = (const float*)d_in[8];
  const float* g1  = (const float*)d_in[9];
  const float* be1 = (const float*)d_in[10];
  const float* W1  = (const float*)d_in[11];
  const float* b1  = (const float*)d_in[12];
  const float* W2  = (const float*)d_in[13];
  const float* b2  = (const float*)d_in[14];
  const float* g2  = (const float*)d_in[15];
  const float* be2 = (const float*)d_in[16];
  float* outf = (float*)d_out;
  char* ws = (char*)d_ws;

  u16*   WQKVT = (u16*)(ws + OFF_WQKVT);
  u16*   WOT   = (u16*)(ws + OFF_WOT);
  u16*   W1T   = (u16*)(ws + OFF_W1T);
  u16*   W2T   = (u16*)(ws + OFF_W2T);
  float* BQKV  = (float*)(ws + OFF_BQKV);
  u16*   XN    = (u16*)(ws + OFF_XN);
  u16*   QKV   = (u16*)(ws + OFF_QKV);
  u16*   AO    = (u16*)(ws + OFF_AO);
  u16*   Hbuf  = (u16*)(ws + OFF_H);
  float* X1    = outf;  // fp32 residual stream #2 lives in d_out

  const dim3 blk(256);
  // weight transposes+convert (grid = (Cc/64, R/64))
  transpose_cvt<<<dim3(16, 16), blk, 0, stream>>>(Wq, WQKVT,               1024, 1024);
  transpose_cvt<<<dim3(16, 16), blk, 0, stream>>>(Wk, WQKVT + 1024 * 1024, 1024, 1024);
  transpose_cvt<<<dim3(16, 16), blk, 0, stream>>>(Wv, WQKVT + 2048 * 1024, 1024, 1024);
  transpose_cvt<<<dim3(16, 16), blk, 0, stream>>>(Wo, WOT,                 1024, 1024);
  transpose_cvt<<<dim3(64, 16), blk, 0, stream>>>(W1, W1T,                 1024, 4096);
  transpose_cvt<<<dim3(16, 64), blk, 0, stream>>>(W2, W2T,                 4096, 1024);
  concat3<<<dim3(12), blk, 0, stream>>>(bq, bk, bv, BQKV);

  // attention sublayer
  ln_kernel<<<dim3(ROWS), blk, 0, stream>>>(x, g1, be1, XN);
  gemm_bt<0, 0><<<dim3(24, 32), blk, 0, stream>>>(XN, WQKVT, BQKV, nullptr,
                                                  QKV, nullptr, ROWS, 3072, 1024);
  attn_band<<<dim3(32, 32), blk, 0, stream>>>(QKV, AO);
  attn_global_rows<<<dim3(512), blk, 0, stream>>>(QKV, AO);
  gemm_bt<2, 1><<<dim3(8, 32), blk, 0, stream>>>(AO, WOT, bo, x,
                                                 nullptr, X1, ROWS, 1024, 1024);

  // FFN sublayer
  ln_kernel<<<dim3(ROWS), blk, 0, stream>>>(X1, g2, be2, XN);
  gemm_bt<1, 0><<<dim3(32, 32), blk, 0, stream>>>(XN, W1T, b1, nullptr,
                                                  Hbuf, nullptr, ROWS, 4096, 1024);
  gemm_bt<2, 1><<<dim3(8, 32), blk, 0, stream>>>(Hbuf, W2T, b2, X1,
                                                 nullptr, outf, ROWS, 1024, 4096);
}

// Round 5
// 472.458 us; speedup vs baseline: 1.3064x; 1.1077x over previous
//
#include <hip/hip_runtime.h>
#include <stdint.h>

// ---------------------------------------------------------------------------
// EncoderBlock: pre-norm transformer block, MI355X (gfx950).
// External dtype: FP32 (per reference). Internal: bf16 MFMA, fp32 accum,
// fp32 residual stream.
// B=2 S=2048 D=1024 H=16 DK=64 DFF=4096 WINDOW=128 GLOBAL=16
// ---------------------------------------------------------------------------

typedef unsigned short u16;
typedef unsigned int   u32;
typedef __attribute__((ext_vector_type(8))) short  short8;  // 8 bf16 (4 VGPRs)
typedef __attribute__((ext_vector_type(4))) float  f32x4;

#define S_LEN   2048
#define D_MODEL 1024
#define ROWS    4096   // B*S

__device__ __forceinline__ float bf2f(u16 u) {
  union { u32 i; float f; } v; v.i = ((u32)u) << 16; return v.f;
}
__device__ __forceinline__ float bflo(u32 u) {
  union { u32 i; float f; } v; v.i = u << 16; return v.f;
}
__device__ __forceinline__ float bfhi(u32 u) {
  union { u32 i; float f; } v; v.i = u & 0xffff0000u; return v.f;
}
__device__ __forceinline__ u16 f2bf(float f) {
  union { float f; u32 i; } v; v.f = f;
  u32 r = v.i + 0x7fffu + ((v.i >> 16) & 1u);
  return (u16)(r >> 16);
}

// Direct global->LDS copy, 16B/lane (m97: +69% GEMM). Data lands at
// wave-uniform LDS base + lane*16.
__device__ __forceinline__ void gld_lds16(const u16* g, u16* l) {
  __attribute__((address_space(3))) u32* lp =
      reinterpret_cast<__attribute__((address_space(3))) u32*>(
          reinterpret_cast<uintptr_t>(l));
  const __attribute__((address_space(1))) u32* gp =
      reinterpret_cast<const __attribute__((address_space(1))) u32*>(
          reinterpret_cast<uintptr_t>(g));
  __builtin_amdgcn_global_load_lds(gp, lp, 16, 0, 0);
}

// k-chunk swizzle: LDS slot s at row R holds global k-chunk (s - (R>>1))&3;
// reader of global chunk kq uses slot (kq + (R>>1))&3. Spreads the 16 rows of
// a fragment read over all 8 bank-quads (2 lanes/bank = free, m136) while
// keeping global_load_lds's lane-contiguous LDS scatter (swizzle applied on
// the GLOBAL address side at staging).

// ---------------------------------------------------------------------------
// GEMM 128x128 (for QKV: N=3072, W1: N=4096 — grids of 768/1024 blocks).
// C[M,N] = A[M,K] @ Bt^T (+bias, opt gelu/residual). A,Bt bf16; bias/res
// fp32. EPI: 0=bias, 1=bias+gelu, 2=bias+residual. OUTF: 0=bf16, 1=fp32 out.
// ---------------------------------------------------------------------------
template <int EPI, int OUTF>
__global__ __launch_bounds__(256) void gemm_bt(
    const u16* __restrict__ A, const u16* __restrict__ Bt,
    const float* __restrict__ bias, const float* res,
    u16* Cb, float* Cf, int M, int N, int K)
{
  __shared__ __attribute__((aligned(16))) u16 As[128 * 32];
  __shared__ __attribute__((aligned(16))) u16 Bs[128 * 32];
  const int tid  = threadIdx.x;
  const int wave = tid >> 6;
  const int lane = tid & 63;
  const int bm = blockIdx.y * 128;
  const int bn = blockIdx.x * 128;
  const int wr = (wave >> 1) * 64;
  const int wc = (wave & 1) * 64;
  const int lm = lane & 15;
  const int kq = lane >> 4;

  f32x4 acc[4][4];
#pragma unroll
  for (int i = 0; i < 4; ++i)
#pragma unroll
    for (int j = 0; j < 4; ++j) acc[i][j] = (f32x4){0.f, 0.f, 0.f, 0.f};

  // staging: lane -> row wave*16+(lane>>2); slot (lane&3) stores global
  // chunk (slot - row>>1)&3. Row+64 has the same (row>>1)&3 -> same kg.
  const int srow = wave * 16 + (lane >> 2);
  const int kg   = (((lane & 3) - (srow >> 1)) & 3) * 8;
  const u16* gA = A  + (size_t)(bm + srow) * K + kg;
  const u16* gB = Bt + (size_t)(bn + srow) * K + kg;
  u16* lA = &As[(wave * 16) * 32];
  u16* lB = &Bs[(wave * 16) * 32];

  for (int k0 = 0; k0 < K; k0 += 32) {
    gld_lds16(gA + k0, lA);
    gld_lds16(gA + (size_t)64 * K + k0, lA + 64 * 32);
    gld_lds16(gB + k0, lB);
    gld_lds16(gB + (size_t)64 * K + k0, lB + 64 * 32);
    __syncthreads();

    short8 af[4], bfv[4];
#pragma unroll
    for (int ti = 0; ti < 4; ++ti) {
      const int Ra = wr + ti * 16 + lm;
      af[ti] = *(const short8*)&As[Ra * 32 + (((kq + (Ra >> 1)) & 3) * 8)];
    }
#pragma unroll
    for (int tj = 0; tj < 4; ++tj) {
      const int Rb = wc + tj * 16 + lm;
      bfv[tj] = *(const short8*)&Bs[Rb * 32 + (((kq + (Rb >> 1)) & 3) * 8)];
    }
#pragma unroll
    for (int ti = 0; ti < 4; ++ti)
#pragma unroll
      for (int tj = 0; tj < 4; ++tj)
        acc[ti][tj] = __builtin_amdgcn_mfma_f32_16x16x32_bf16(
            af[ti], bfv[tj], acc[ti][tj], 0, 0, 0);
    __syncthreads();
  }

  const int r0 = (lane >> 4) * 4;
#pragma unroll
  for (int ti = 0; ti < 4; ++ti) {
#pragma unroll
    for (int r = 0; r < 4; ++r) {
      const int grow = bm + wr + ti * 16 + r0 + r;
#pragma unroll
      for (int tj = 0; tj < 4; ++tj) {
        const int gcol = bn + wc + tj * 16 + lm;
        const size_t idx = (size_t)grow * N + gcol;
        float v = acc[ti][tj][r] + bias[gcol];
        if (EPI == 1) v = 0.5f * v * (1.0f + erff(v * 0.70710678118654752f));
        if (EPI == 2) v += res[idx];
        if (OUTF) Cf[idx] = v;
        else      Cb[idx] = f2bf(v);
      }
    }
  }
}

// ---------------------------------------------------------------------------
// Skinny GEMM 64x128 tile (for Wo/W2: N=1024 -> grid (8,64) = 512 blocks =
// 2 blocks/CU; the 128x128 tile gave only 256 blocks = 1/CU = latency-bound,
// measured occupancy 10.8%, 310 TF). 2x2 waves, each 32x64 (2x4 frags).
// ---------------------------------------------------------------------------
template <int EPI, int OUTF>
__global__ __launch_bounds__(256) void gemm_bt_sk(
    const u16* __restrict__ A, const u16* __restrict__ Bt,
    const float* __restrict__ bias, const float* res,
    u16* Cb, float* Cf, int M, int N, int K)
{
  __shared__ __attribute__((aligned(16))) u16 As[64 * 32];
  __shared__ __attribute__((aligned(16))) u16 Bs[128 * 32];
  const int tid  = threadIdx.x;
  const int wave = tid >> 6;
  const int lane = tid & 63;
  const int bm = blockIdx.y * 64;
  const int bn = blockIdx.x * 128;
  const int wr = (wave >> 1) * 32;
  const int wc = (wave & 1) * 64;
  const int lm = lane & 15;
  const int kq = lane >> 4;

  f32x4 acc[2][4];
#pragma unroll
  for (int i = 0; i < 2; ++i)
#pragma unroll
    for (int j = 0; j < 4; ++j) acc[i][j] = (f32x4){0.f, 0.f, 0.f, 0.f};

  const int srow = wave * 16 + (lane >> 2);
  const int kg   = (((lane & 3) - (srow >> 1)) & 3) * 8;
  const u16* gA = A  + (size_t)(bm + srow) * K + kg;
  const u16* gB = Bt + (size_t)(bn + srow) * K + kg;
  u16* lA = &As[(wave * 16) * 32];
  u16* lB = &Bs[(wave * 16) * 32];

  for (int k0 = 0; k0 < K; k0 += 32) {
    gld_lds16(gA + k0, lA);
    gld_lds16(gB + k0, lB);
    gld_lds16(gB + (size_t)64 * K + k0, lB + 64 * 32);
    __syncthreads();

    short8 af[2], bfv[4];
#pragma unroll
    for (int ti = 0; ti < 2; ++ti) {
      const int Ra = wr + ti * 16 + lm;
      af[ti] = *(const short8*)&As[Ra * 32 + (((kq + (Ra >> 1)) & 3) * 8)];
    }
#pragma unroll
    for (int tj = 0; tj < 4; ++tj) {
      const int Rb = wc + tj * 16 + lm;
      bfv[tj] = *(const short8*)&Bs[Rb * 32 + (((kq + (Rb >> 1)) & 3) * 8)];
    }
#pragma unroll
    for (int ti = 0; ti < 2; ++ti)
#pragma unroll
      for (int tj = 0; tj < 4; ++tj)
        acc[ti][tj] = __builtin_amdgcn_mfma_f32_16x16x32_bf16(
            af[ti], bfv[tj], acc[ti][tj], 0, 0, 0);
    __syncthreads();
  }

  const int r0 = (lane >> 4) * 4;
#pragma unroll
  for (int ti = 0; ti < 2; ++ti) {
#pragma unroll
    for (int r = 0; r < 4; ++r) {
      const int grow = bm + wr + ti * 16 + r0 + r;
#pragma unroll
      for (int tj = 0; tj < 4; ++tj) {
        const int gcol = bn + wc + tj * 16 + lm;
        const size_t idx = (size_t)grow * N + gcol;
        float v = acc[ti][tj][r] + bias[gcol];
        if (EPI == 1) v = 0.5f * v * (1.0f + erff(v * 0.70710678118654752f));
        if (EPI == 2) v += res[idx];
        if (OUTF) Cf[idx] = v;
        else      Cb[idx] = f2bf(v);
      }
    }
  }
}

// ---------------------------------------------------------------------------
// LayerNorm: fp32 in, bf16 out. One block per row (D=1024).
// ---------------------------------------------------------------------------
__global__ __launch_bounds__(256) void ln_kernel(
    const float* __restrict__ x, const float* __restrict__ g,
    const float* __restrict__ b, u16* __restrict__ o)
{
  const int row = blockIdx.x;
  const int t = threadIdx.x;
  float4 v = *(const float4*)(x + (size_t)row * D_MODEL + t * 4);
  float s  = v.x + v.y + v.z + v.w;
  float ss = v.x * v.x + v.y * v.y + v.z * v.z + v.w * v.w;
#pragma unroll
  for (int off = 32; off > 0; off >>= 1) {
    s  += __shfl_down(s, off);
    ss += __shfl_down(ss, off);
  }
  __shared__ float sm[4], ssm[4], stat[2];
  if ((t & 63) == 0) { sm[t >> 6] = s; ssm[t >> 6] = ss; }
  __syncthreads();
  if (t == 0) {
    float S = sm[0] + sm[1] + sm[2] + sm[3];
    float SS = ssm[0] + ssm[1] + ssm[2] + ssm[3];
    float mu = S * (1.0f / 1024.0f);
    float var = SS * (1.0f / 1024.0f) - mu * mu;
    stat[0] = mu;
    stat[1] = rsqrtf(fmaxf(var, 0.0f) + 1e-5f);
  }
  __syncthreads();
  const float mu = stat[0], rstd = stat[1];
  float4 gg = *(const float4*)(g + t * 4);
  float4 bb = *(const float4*)(b + t * 4);
  u16 o0 = f2bf((v.x - mu) * rstd * gg.x + bb.x);
  u16 o1 = f2bf((v.y - mu) * rstd * gg.y + bb.y);
  u16 o2 = f2bf((v.z - mu) * rstd * gg.z + bb.z);
  u16 o3 = f2bf((v.w - mu) * rstd * gg.w + bb.w);
  uint2 w;
  w.x = (u32)o0 | ((u32)o1 << 16);
  w.y = (u32)o2 | ((u32)o3 << 16);
  *(uint2*)(o + (size_t)row * D_MODEL + t * 4) = w;
}

// ---------------------------------------------------------------------------
// Banded attention, MFMA flash style (unchanged from round 4 — passed).
// ---------------------------------------------------------------------------
__global__ __launch_bounds__(256) void attn_band(
    const u16* __restrict__ qkv, u16* __restrict__ out)
{
  const int t    = threadIdx.x;
  const int w    = t >> 6;
  const int lane = t & 63;
  const int m    = lane & 15;
  const int quad = lane >> 4;
  const int bh   = blockIdx.y;
  const int b    = bh >> 4, h = bh & 15;
  const int i0   = blockIdx.x * 64;
  const size_t bb = (size_t)b * S_LEN;

  __shared__ __attribute__((aligned(16))) u16 Ks[32 * 72];
  __shared__ __attribute__((aligned(16))) u16 Vt[64 * 40];
  __shared__ __attribute__((aligned(16))) u16 Ps[4][16 * 40];

  const u16* qrow = qkv + (bb + i0 + 16 * w + m) * 3072 + h * 64;
  const short8 aq0 = *(const short8*)(qrow + quad * 8);
  const short8 aq1 = *(const short8*)(qrow + 32 + quad * 8);

  f32x4 Ov[4];
#pragma unroll
  for (int td = 0; td < 4; ++td) Ov[td] = (f32x4){0.f, 0.f, 0.f, 0.f};
  float mP[4] = {-1e30f, -1e30f, -1e30f, -1e30f};
  float lS[4] = {0.f, 0.f, 0.f, 0.f};

  const int iB = i0 + 16 * w + quad * 4;

  const int lo = max(32, i0 - 128);
  const int hi = min(S_LEN, i0 + 192);
  const int nChunks = 1 + (hi - lo) / 32;

  const int skr = t >> 3;
  const int skc = (t & 7) * 8;

  for (int c = 0; c < nChunks; ++c) {
    const int j0 = (c == 0) ? 0 : lo + (c - 1) * 32;
    __syncthreads();
    {
      const u16* src = qkv + (bb + j0 + skr) * 3072 + 1024 + h * 64 + skc;
      uint4 kk = *(const uint4*)src;
      uint4 vv = *(const uint4*)(src + 1024);
      *(uint4*)&Ks[skr * 72 + skc] = kk;
      const u16 vs[8] = {
        (u16)(vv.x & 0xffffu), (u16)(vv.x >> 16),
        (u16)(vv.y & 0xffffu), (u16)(vv.y >> 16),
        (u16)(vv.z & 0xffffu), (u16)(vv.z >> 16),
        (u16)(vv.w & 0xffffu), (u16)(vv.w >> 16)};
#pragma unroll
      for (int i = 0; i < 8; ++i) Vt[(skc + i) * 40 + skr] = vs[i];
    }
    __syncthreads();

    const short8 b00 = *(const short8*)&Ks[m * 72 + quad * 8];
    const short8 b01 = *(const short8*)&Ks[m * 72 + 32 + quad * 8];
    const short8 b10 = *(const short8*)&Ks[(16 + m) * 72 + quad * 8];
    const short8 b11 = *(const short8*)&Ks[(16 + m) * 72 + 32 + quad * 8];
    f32x4 s0 = (f32x4){0.f, 0.f, 0.f, 0.f};
    f32x4 s1 = (f32x4){0.f, 0.f, 0.f, 0.f};
    s0 = __builtin_amdgcn_mfma_f32_16x16x32_bf16(aq0, b00, s0, 0, 0, 0);
    s0 = __builtin_amdgcn_mfma_f32_16x16x32_bf16(aq1, b01, s0, 0, 0, 0);
    s1 = __builtin_amdgcn_mfma_f32_16x16x32_bf16(aq0, b10, s1, 0, 0, 0);
    s1 = __builtin_amdgcn_mfma_f32_16x16x32_bf16(aq1, b11, s1, 0, 0, 0);

    const int jA = j0 + m, jB = j0 + 16 + m;
#pragma unroll
    for (int r = 0; r < 4; ++r) {
      const int iG = iB + r;
      const int da = iG - jA, db = iG - jB;
      s0[r] = ((jA < 16) || (da >= -128 && da <= 128)) ? s0[r] * 0.125f : -1e30f;
      s1[r] = ((jB < 16) || (db >= -128 && db <= 128)) ? s1[r] * 0.125f : -1e30f;
    }

    float al[4];
#pragma unroll
    for (int r = 0; r < 4; ++r) {
      float mx = fmaxf(s0[r], s1[r]);
      mx = fmaxf(mx, __shfl_xor(mx, 1, 16));
      mx = fmaxf(mx, __shfl_xor(mx, 2, 16));
      mx = fmaxf(mx, __shfl_xor(mx, 4, 16));
      mx = fmaxf(mx, __shfl_xor(mx, 8, 16));
      const float mn = fmaxf(mP[r], mx);
      al[r] = __expf(mP[r] - mn);
      mP[r] = mn;
      const float p0 = __expf(s0[r] - mn);
      const float p1 = __expf(s1[r] - mn);
      float ps = p0 + p1;
      ps += __shfl_xor(ps, 1, 16);
      ps += __shfl_xor(ps, 2, 16);
      ps += __shfl_xor(ps, 4, 16);
      ps += __shfl_xor(ps, 8, 16);
      lS[r] = lS[r] * al[r] + ps;
      Ps[w][(quad * 4 + r) * 40 + m]      = f2bf(p0);
      Ps[w][(quad * 4 + r) * 40 + 16 + m] = f2bf(p1);
    }
#pragma unroll
    for (int td = 0; td < 4; ++td)
#pragma unroll
      for (int r = 0; r < 4; ++r) Ov[td][r] *= al[r];

    const short8 pa = *(const short8*)&Ps[w][m * 40 + quad * 8];
#pragma unroll
    for (int td = 0; td < 4; ++td) {
      const short8 bv = *(const short8*)&Vt[(td * 16 + m) * 40 + quad * 8];
      Ov[td] = __builtin_amdgcn_mfma_f32_16x16x32_bf16(pa, bv, Ov[td], 0, 0, 0);
    }
  }

  if (i0 + 16 * w >= 16) {
    float inv[4];
#pragma unroll
    for (int r = 0; r < 4; ++r) inv[r] = 1.0f / lS[r];
#pragma unroll
    for (int td = 0; td < 4; ++td)
#pragma unroll
      for (int r = 0; r < 4; ++r)
        out[(bb + iB + r) * 1024 + h * 64 + td * 16 + m] =
            f2bf(Ov[td][r] * inv[r]);
  }
}

// ---------------------------------------------------------------------------
// Global rows (i < 16): full attention over all 2048 keys. Block per (b,h,i).
// ---------------------------------------------------------------------------
__global__ __launch_bounds__(256) void attn_global_rows(
    const u16* __restrict__ qkv, u16* __restrict__ out)
{
  const int t  = threadIdx.x;
  const int gi = blockIdx.x;          // 512 = B*H*16
  const int i  = gi & 15;
  const int bh = gi >> 4;
  const int b  = bh >> 4, h = bh & 15;
  __shared__ float Ss[2048];
  __shared__ float qs[64];
  __shared__ float red[4];
  __shared__ float ML[2];
  __shared__ float Opart[4][64];
  const size_t bb = (size_t)b * S_LEN;

  if (t < 64) qs[t] = bf2f(qkv[(bb + i) * 3072 + h * 64 + t]) * 0.125f;
  __syncthreads();

  for (int c = 0; c < 8; ++c) {
    const u16* kr = qkv + (bb + c * 256 + t) * 3072 + 1024 + h * 64;
    float acc = 0.f;
#pragma unroll
    for (int q = 0; q < 8; ++q) {
      uint4 rr = *(const uint4*)(kr + q * 8);
      acc += qs[q * 8 + 0] * bflo(rr.x) + qs[q * 8 + 1] * bfhi(rr.x)
           + qs[q * 8 + 2] * bflo(rr.y) + qs[q * 8 + 3] * bfhi(rr.y)
           + qs[q * 8 + 4] * bflo(rr.z) + qs[q * 8 + 5] * bfhi(rr.z)
           + qs[q * 8 + 6] * bflo(rr.w) + qs[q * 8 + 7] * bfhi(rr.w);
    }
    Ss[c * 256 + t] = acc;
  }
  __syncthreads();

  float m = -1e30f;
#pragma unroll
  for (int c = 0; c < 8; ++c) m = fmaxf(m, Ss[c * 256 + t]);
#pragma unroll
  for (int off = 32; off > 0; off >>= 1) m = fmaxf(m, __shfl_xor(m, off));
  if ((t & 63) == 0) red[t >> 6] = m;
  __syncthreads();
  if (t == 0) ML[0] = fmaxf(fmaxf(red[0], red[1]), fmaxf(red[2], red[3]));
  __syncthreads();
  const float M = ML[0];
  float ls = 0.f;
#pragma unroll
  for (int c = 0; c < 8; ++c) {
    float p = __expf(Ss[c * 256 + t] - M);
    Ss[c * 256 + t] = p;
    ls += p;
  }
#pragma unroll
  for (int off = 32; off > 0; off >>= 1) ls += __shfl_xor(ls, off);
  __syncthreads();
  if ((t & 63) == 0) red[t >> 6] = ls;
  __syncthreads();
  if (t == 0) ML[1] = red[0] + red[1] + red[2] + red[3];
  __syncthreads();
  const float L = ML[1];

  const int d  = t & 63;
  const int qd = t >> 6;
  float oacc = 0.f;
  for (int c = 0; c < 8; ++c) {
#pragma unroll 8
    for (int jl = 0; jl < 64; ++jl) {
      const int j = c * 256 + qd * 64 + jl;
      oacc += Ss[j] * bf2f(qkv[(bb + j) * 3072 + 2048 + h * 64 + d]);
    }
  }
  Opart[qd][d] = oacc;
  __syncthreads();
  if (t < 64) {
    float o = (Opart[0][t] + Opart[1][t] + Opart[2][t] + Opart[3][t]) / L;
    out[(bb + i) * 1024 + h * 64 + t] = f2bf(o);
  }
}

// ---------------------------------------------------------------------------
// Transpose + fp32->bf16 convert: out[Cc][R] bf16, out[c][r] = in[r][c].
// ---------------------------------------------------------------------------
__global__ __launch_bounds__(256) void transpose_cvt(
    const float* __restrict__ in, u16* __restrict__ outp, int R, int Cc)
{
  __shared__ u16 tile[64][65];
  const int t = threadIdx.x;
  const int tr = blockIdx.y * 64, tc = blockIdx.x * 64;
  const int lr = t >> 2, lc0 = (t & 3) * 16;
  const float* src = in + (size_t)(tr + lr) * Cc + tc + lc0;
  float4 a0 = *(const float4*)(src);
  float4 a1 = *(const float4*)(src + 4);
  float4 a2 = *(const float4*)(src + 8);
  float4 a3 = *(const float4*)(src + 12);
  const float vals[16] = {a0.x, a0.y, a0.z, a0.w, a1.x, a1.y, a1.z, a1.w,
                          a2.x, a2.y, a2.z, a2.w, a3.x, a3.y, a3.z, a3.w};
#pragma unroll
  for (int q = 0; q < 16; ++q) tile[lr][lc0 + q] = f2bf(vals[q]);
  __syncthreads();
  u16* dst = outp + (size_t)(tc + lr) * R + tr + lc0;
  u32 w[8];
#pragma unroll
  for (int q = 0; q < 8; ++q)
    w[q] = (u32)tile[lc0 + 2 * q][lr] | ((u32)tile[lc0 + 2 * q + 1][lr] << 16);
  uint4 s0; s0.x = w[0]; s0.y = w[1]; s0.z = w[2]; s0.w = w[3];
  uint4 s1; s1.x = w[4]; s1.y = w[5]; s1.z = w[6]; s1.w = w[7];
  *(uint4*)dst = s0;
  *(uint4*)(dst + 8) = s1;
}

__global__ __launch_bounds__(256) void concat3(
    const float* __restrict__ a, const float* __restrict__ b,
    const float* __restrict__ c, float* __restrict__ o)
{
  const int i = blockIdx.x * 256 + threadIdx.x;  // grid 12 -> 3072
  if (i < 1024) o[i] = a[i];
  else if (i < 2048) o[i] = b[i - 1024];
  else o[i] = c[i - 2048];
}

// ---------------------------------------------------------------------------
// workspace layout (bytes) — ~67 MB (validated: rounds 3-4 passed).
// ---------------------------------------------------------------------------
static const size_t OFF_WQKVT = 0;                                   // bf16 [3072][1024]
static const size_t OFF_WOT   = OFF_WQKVT + (size_t)3072 * 1024 * 2; // bf16 [1024][1024]
static const size_t OFF_W1T   = OFF_WOT   + (size_t)1024 * 1024 * 2; // bf16 [4096][1024]
static const size_t OFF_W2T   = OFF_W1T   + (size_t)4096 * 1024 * 2; // bf16 [1024][4096]
static const size_t OFF_BQKV  = OFF_W2T   + (size_t)1024 * 4096 * 2; // fp32 [3072]
static const size_t OFF_XN    = OFF_BQKV  + 16384;                   // bf16 [4096][1024]
static const size_t OFF_QKV   = OFF_XN    + (size_t)4096 * 1024 * 2; // bf16 [4096][3072]
static const size_t OFF_AO    = OFF_QKV   + (size_t)4096 * 3072 * 2; // bf16 [4096][1024]
static const size_t OFF_H     = OFF_QKV;  // bf16 [4096][4096], aliases QKV+AO

extern "C" void kernel_launch(void* const* d_in, const int* in_sizes, int n_in,
                              void* d_out, int out_size, void* d_ws, size_t ws_size,
                              hipStream_t stream)
{
  const float* x   = (const float*)d_in[0];
  const float* Wq  = (const float*)d_in[1];
  const float* bq  = (const float*)d_in[2];
  const float* Wk  = (const float*)d_in[3];
  const float* bk  = (const float*)d_in[4];
  const float* Wv  = (const float*)d_in[5];
  const float* bv  = (const float*)d_in[6];
  const float* Wo  = (const float*)d_in[7];
  const float* bo  = (const float*)d_in[8];
  const float* g1  = (const float*)d_in[9];
  const float* be1 = (const float*)d_in[10];
  const float* W1  = (const float*)d_in[11];
  const float* b1  = (const float*)d_in[12];
  const float* W2  = (const float*)d_in[13];
  const float* b2  = (const float*)d_in[14];
  const float* g2  = (const float*)d_in[15];
  const float* be2 = (const float*)d_in[16];
  float* outf = (float*)d_out;
  char* ws = (char*)d_ws;

  u16*   WQKVT = (u16*)(ws + OFF_WQKVT);
  u16*   WOT   = (u16*)(ws + OFF_WOT);
  u16*   W1T   = (u16*)(ws + OFF_W1T);
  u16*   W2T   = (u16*)(ws + OFF_W2T);
  float* BQKV  = (float*)(ws + OFF_BQKV);
  u16*   XN    = (u16*)(ws + OFF_XN);
  u16*   QKV   = (u16*)(ws + OFF_QKV);
  u16*   AO    = (u16*)(ws + OFF_AO);
  u16*   Hbuf  = (u16*)(ws + OFF_H);
  float* X1    = outf;  // fp32 residual stream #2 lives in d_out

  const dim3 blk(256);
  transpose_cvt<<<dim3(16, 16), blk, 0, stream>>>(Wq, WQKVT,               1024, 1024);
  transpose_cvt<<<dim3(16, 16), blk, 0, stream>>>(Wk, WQKVT + 1024 * 1024, 1024, 1024);
  transpose_cvt<<<dim3(16, 16), blk, 0, stream>>>(Wv, WQKVT + 2048 * 1024, 1024, 1024);
  transpose_cvt<<<dim3(16, 16), blk, 0, stream>>>(Wo, WOT,                 1024, 1024);
  transpose_cvt<<<dim3(64, 16), blk, 0, stream>>>(W1, W1T,                 1024, 4096);
  transpose_cvt<<<dim3(16, 64), blk, 0, stream>>>(W2, W2T,                 4096, 1024);
  concat3<<<dim3(12), blk, 0, stream>>>(bq, bk, bv, BQKV);

  // attention sublayer
  ln_kernel<<<dim3(ROWS), blk, 0, stream>>>(x, g1, be1, XN);
  gemm_bt<0, 0><<<dim3(24, 32), blk, 0, stream>>>(XN, WQKVT, BQKV, nullptr,
                                                  QKV, nullptr, ROWS, 3072, 1024);
  attn_band<<<dim3(32, 32), blk, 0, stream>>>(QKV, AO);
  attn_global_rows<<<dim3(512), blk, 0, stream>>>(QKV, AO);
  gemm_bt_sk<2, 1><<<dim3(8, 64), blk, 0, stream>>>(AO, WOT, bo, x,
                                                    nullptr, X1, ROWS, 1024, 1024);

  // FFN sublayer
  ln_kernel<<<dim3(ROWS), blk, 0, stream>>>(X1, g2, be2, XN);
  gemm_bt<1, 0><<<dim3(32, 32), blk, 0, stream>>>(XN, W1T, b1, nullptr,
                                                  Hbuf, nullptr, ROWS, 4096, 1024);
  gemm_bt_sk<2, 1><<<dim3(8, 64), blk, 0, stream>>>(Hbuf, W2T, b2, X1,
                                                    nullptr, outf, ROWS, 1024, 4096);
}

// Round 6
// 458.538 us; speedup vs baseline: 1.3460x; 1.0304x over previous
//
#include <hip/hip_runtime.h>
#include <stdint.h>

// ---------------------------------------------------------------------------
// EncoderBlock: pre-norm transformer block, MI355X (gfx950).
// External dtype: FP32. Internal: bf16 MFMA, fp32 accum, fp32 residual.
// B=2 S=2048 D=1024 H=16 DK=64 DFF=4096 WINDOW=128 GLOBAL=16
// ---------------------------------------------------------------------------

typedef unsigned short u16;
typedef unsigned int   u32;
typedef __attribute__((ext_vector_type(8))) short  short8;  // 8 bf16 (4 VGPRs)
typedef __attribute__((ext_vector_type(4))) float  f32x4;

#define S_LEN   2048
#define D_MODEL 1024
#define ROWS    4096   // B*S

__device__ __forceinline__ float bf2f(u16 u) {
  union { u32 i; float f; } v; v.i = ((u32)u) << 16; return v.f;
}
__device__ __forceinline__ float bflo(u32 u) {
  union { u32 i; float f; } v; v.i = u << 16; return v.f;
}
__device__ __forceinline__ float bfhi(u32 u) {
  union { u32 i; float f; } v; v.i = u & 0xffff0000u; return v.f;
}
__device__ __forceinline__ u16 f2bf(float f) {
  union { float f; u32 i; } v; v.f = f;
  u32 r = v.i + 0x7fffu + ((v.i >> 16) & 1u);
  return (u16)(r >> 16);
}

// Direct global->LDS copy, 16B/lane (m97). Lands at wave base + lane*16.
__device__ __forceinline__ void gld_lds16(const u16* g, u16* l) {
  __attribute__((address_space(3))) u32* lp =
      reinterpret_cast<__attribute__((address_space(3))) u32*>(
          reinterpret_cast<uintptr_t>(l));
  const __attribute__((address_space(1))) u32* gp =
      reinterpret_cast<const __attribute__((address_space(1))) u32*>(
          reinterpret_cast<uintptr_t>(g));
  __builtin_amdgcn_global_load_lds(gp, lp, 16, 0, 0);
}

// k-chunk swizzle (round-5 verified: SQ_LDS_BANK_CONFLICT 4.19M -> 0):
// LDS slot s at row R holds global k-chunk (s-(R>>1))&3; reader of chunk kq
// uses slot (kq+(R>>1))&3. Swizzle applied on the GLOBAL address at staging
// so global_load_lds's lane-contiguous LDS scatter stays legal.

// ---------------------------------------------------------------------------
// GEMM 128x128 (QKV: N=3072, W1: N=4096 — grids 768/1024 blocks).
// EPI: 0=bias, 1=bias+gelu. OUTF: 0=bf16, 1=fp32 out.
// ---------------------------------------------------------------------------
template <int EPI, int OUTF>
__global__ __launch_bounds__(256) void gemm_bt(
    const u16* __restrict__ A, const u16* __restrict__ Bt,
    const float* __restrict__ bias, const float* res,
    u16* Cb, float* Cf, int M, int N, int K)
{
  __shared__ __attribute__((aligned(16))) u16 As[128 * 32];
  __shared__ __attribute__((aligned(16))) u16 Bs[128 * 32];
  const int tid  = threadIdx.x;
  const int wave = tid >> 6;
  const int lane = tid & 63;
  const int bm = blockIdx.y * 128;
  const int bn = blockIdx.x * 128;
  const int wr = (wave >> 1) * 64;
  const int wc = (wave & 1) * 64;
  const int lm = lane & 15;
  const int kq = lane >> 4;

  f32x4 acc[4][4];
#pragma unroll
  for (int i = 0; i < 4; ++i)
#pragma unroll
    for (int j = 0; j < 4; ++j) acc[i][j] = (f32x4){0.f, 0.f, 0.f, 0.f};

  const int srow = wave * 16 + (lane >> 2);
  const int kg   = (((lane & 3) - (srow >> 1)) & 3) * 8;
  const u16* gA = A  + (size_t)(bm + srow) * K + kg;
  const u16* gB = Bt + (size_t)(bn + srow) * K + kg;
  u16* lA = &As[(wave * 16) * 32];
  u16* lB = &Bs[(wave * 16) * 32];

  for (int k0 = 0; k0 < K; k0 += 32) {
    gld_lds16(gA + k0, lA);
    gld_lds16(gA + (size_t)64 * K + k0, lA + 64 * 32);
    gld_lds16(gB + k0, lB);
    gld_lds16(gB + (size_t)64 * K + k0, lB + 64 * 32);
    __syncthreads();

    short8 af[4], bfv[4];
#pragma unroll
    for (int ti = 0; ti < 4; ++ti) {
      const int Ra = wr + ti * 16 + lm;
      af[ti] = *(const short8*)&As[Ra * 32 + (((kq + (Ra >> 1)) & 3) * 8)];
    }
#pragma unroll
    for (int tj = 0; tj < 4; ++tj) {
      const int Rb = wc + tj * 16 + lm;
      bfv[tj] = *(const short8*)&Bs[Rb * 32 + (((kq + (Rb >> 1)) & 3) * 8)];
    }
#pragma unroll
    for (int ti = 0; ti < 4; ++ti)
#pragma unroll
      for (int tj = 0; tj < 4; ++tj)
        acc[ti][tj] = __builtin_amdgcn_mfma_f32_16x16x32_bf16(
            af[ti], bfv[tj], acc[ti][tj], 0, 0, 0);
    __syncthreads();
  }

  const int r0 = (lane >> 4) * 4;
#pragma unroll
  for (int ti = 0; ti < 4; ++ti) {
#pragma unroll
    for (int r = 0; r < 4; ++r) {
      const int grow = bm + wr + ti * 16 + r0 + r;
#pragma unroll
      for (int tj = 0; tj < 4; ++tj) {
        const int gcol = bn + wc + tj * 16 + lm;
        const size_t idx = (size_t)grow * N + gcol;
        float v = acc[ti][tj][r] + bias[gcol];
        if (EPI == 1) v = 0.5f * v * (1.0f + erff(v * 0.70710678118654752f));
        if (OUTF) Cf[idx] = v;
        else      Cb[idx] = f2bf(v);
      }
    }
  }
}

// ---------------------------------------------------------------------------
// Split-K GEMM (Wo/W2: N=1024). 128x128 tile, grid (N/128, M/128, 2) =
// 512 blocks = 2/CU. Block z computes K-range [z*KH, (z+1)*KH) and writes a
// bf16 partial to Pz. Bias/residual applied in reduce2. Round-5's skinny
// tile (8 MFMA/K-step) stayed latency-bound at 430 TF; this restores the
// 16-MFMA K-step while keeping the grid at 2 blocks/CU.
// ---------------------------------------------------------------------------
__global__ __launch_bounds__(256) void gemm_sp(
    const u16* __restrict__ A, const u16* __restrict__ Bt,
    u16* __restrict__ P0, u16* __restrict__ P1,
    int M, int N, int K, int KH)
{
  __shared__ __attribute__((aligned(16))) u16 As[128 * 32];
  __shared__ __attribute__((aligned(16))) u16 Bs[128 * 32];
  const int tid  = threadIdx.x;
  const int wave = tid >> 6;
  const int lane = tid & 63;
  const int bm = blockIdx.y * 128;
  const int bn = blockIdx.x * 128;
  const int kz = blockIdx.z;
  u16* P = kz ? P1 : P0;
  const int wr = (wave >> 1) * 64;
  const int wc = (wave & 1) * 64;
  const int lm = lane & 15;
  const int kq = lane >> 4;

  f32x4 acc[4][4];
#pragma unroll
  for (int i = 0; i < 4; ++i)
#pragma unroll
    for (int j = 0; j < 4; ++j) acc[i][j] = (f32x4){0.f, 0.f, 0.f, 0.f};

  const int srow = wave * 16 + (lane >> 2);
  const int kg   = (((lane & 3) - (srow >> 1)) & 3) * 8;
  const u16* gA = A  + (size_t)(bm + srow) * K + kz * KH + kg;
  const u16* gB = Bt + (size_t)(bn + srow) * K + kz * KH + kg;
  u16* lA = &As[(wave * 16) * 32];
  u16* lB = &Bs[(wave * 16) * 32];

  for (int k0 = 0; k0 < KH; k0 += 32) {
    gld_lds16(gA + k0, lA);
    gld_lds16(gA + (size_t)64 * K + k0, lA + 64 * 32);
    gld_lds16(gB + k0, lB);
    gld_lds16(gB + (size_t)64 * K + k0, lB + 64 * 32);
    __syncthreads();

    short8 af[4], bfv[4];
#pragma unroll
    for (int ti = 0; ti < 4; ++ti) {
      const int Ra = wr + ti * 16 + lm;
      af[ti] = *(const short8*)&As[Ra * 32 + (((kq + (Ra >> 1)) & 3) * 8)];
    }
#pragma unroll
    for (int tj = 0; tj < 4; ++tj) {
      const int Rb = wc + tj * 16 + lm;
      bfv[tj] = *(const short8*)&Bs[Rb * 32 + (((kq + (Rb >> 1)) & 3) * 8)];
    }
#pragma unroll
    for (int ti = 0; ti < 4; ++ti)
#pragma unroll
      for (int tj = 0; tj < 4; ++tj)
        acc[ti][tj] = __builtin_amdgcn_mfma_f32_16x16x32_bf16(
            af[ti], bfv[tj], acc[ti][tj], 0, 0, 0);
    __syncthreads();
  }

  const int r0 = (lane >> 4) * 4;
#pragma unroll
  for (int ti = 0; ti < 4; ++ti) {
#pragma unroll
    for (int r = 0; r < 4; ++r) {
      const int grow = bm + wr + ti * 16 + r0 + r;
#pragma unroll
      for (int tj = 0; tj < 4; ++tj) {
        const int gcol = bn + wc + tj * 16 + lm;
        P[(size_t)grow * N + gcol] = f2bf(acc[ti][tj][r]);
      }
    }
  }
}

// out[idx] = P0[idx] + P1[idx] + bias[col] + res[idx]   (N fixed = 1024)
// res and out may alias (same idx read->write per thread).
__global__ __launch_bounds__(256) void reduce2(
    const u16* __restrict__ P0, const u16* __restrict__ P1,
    const float* __restrict__ bias, const float* res, float* out)
{
  const size_t base = ((size_t)blockIdx.x * 256 + threadIdx.x) * 8;
  const int col = (int)(base & 1023);
  uint4 p0 = *(const uint4*)(P0 + base);
  uint4 p1 = *(const uint4*)(P1 + base);
  float4 b0 = *(const float4*)(bias + col);
  float4 b1 = *(const float4*)(bias + col + 4);
  float4 r0 = *(const float4*)(res + base);
  float4 r1 = *(const float4*)(res + base + 4);
  float4 o0, o1;
  o0.x = bflo(p0.x) + bflo(p1.x) + b0.x + r0.x;
  o0.y = bfhi(p0.x) + bfhi(p1.x) + b0.y + r0.y;
  o0.z = bflo(p0.y) + bflo(p1.y) + b0.z + r0.z;
  o0.w = bfhi(p0.y) + bfhi(p1.y) + b0.w + r0.w;
  o1.x = bflo(p0.z) + bflo(p1.z) + b1.x + r1.x;
  o1.y = bfhi(p0.z) + bfhi(p1.z) + b1.y + r1.y;
  o1.z = bflo(p0.w) + bflo(p1.w) + b1.z + r1.z;
  o1.w = bfhi(p0.w) + bfhi(p1.w) + b1.w + r1.w;
  *(float4*)(out + base) = o0;
  *(float4*)(out + base + 4) = o1;
}

// ---------------------------------------------------------------------------
// LayerNorm: fp32 in, bf16 out. One block per row (D=1024).
// ---------------------------------------------------------------------------
__global__ __launch_bounds__(256) void ln_kernel(
    const float* __restrict__ x, const float* __restrict__ g,
    const float* __restrict__ b, u16* __restrict__ o)
{
  const int row = blockIdx.x;
  const int t = threadIdx.x;
  float4 v = *(const float4*)(x + (size_t)row * D_MODEL + t * 4);
  float s  = v.x + v.y + v.z + v.w;
  float ss = v.x * v.x + v.y * v.y + v.z * v.z + v.w * v.w;
#pragma unroll
  for (int off = 32; off > 0; off >>= 1) {
    s  += __shfl_down(s, off);
    ss += __shfl_down(ss, off);
  }
  __shared__ float sm[4], ssm[4], stat[2];
  if ((t & 63) == 0) { sm[t >> 6] = s; ssm[t >> 6] = ss; }
  __syncthreads();
  if (t == 0) {
    float S = sm[0] + sm[1] + sm[2] + sm[3];
    float SS = ssm[0] + ssm[1] + ssm[2] + ssm[3];
    float mu = S * (1.0f / 1024.0f);
    float var = SS * (1.0f / 1024.0f) - mu * mu;
    stat[0] = mu;
    stat[1] = rsqrtf(fmaxf(var, 0.0f) + 1e-5f);
  }
  __syncthreads();
  const float mu = stat[0], rstd = stat[1];
  float4 gg = *(const float4*)(g + t * 4);
  float4 bb = *(const float4*)(b + t * 4);
  u16 o0 = f2bf((v.x - mu) * rstd * gg.x + bb.x);
  u16 o1 = f2bf((v.y - mu) * rstd * gg.y + bb.y);
  u16 o2 = f2bf((v.z - mu) * rstd * gg.z + bb.z);
  u16 o3 = f2bf((v.w - mu) * rstd * gg.w + bb.w);
  uint2 w;
  w.x = (u32)o0 | ((u32)o1 << 16);
  w.y = (u32)o2 | ((u32)o3 << 16);
  *(uint2*)(o + (size_t)row * D_MODEL + t * 4) = w;
}

// ---------------------------------------------------------------------------
// Banded attention, MFMA flash style (rounds 4-5 verified).
// ---------------------------------------------------------------------------
__global__ __launch_bounds__(256) void attn_band(
    const u16* __restrict__ qkv, u16* __restrict__ out)
{
  const int t    = threadIdx.x;
  const int w    = t >> 6;
  const int lane = t & 63;
  const int m    = lane & 15;
  const int quad = lane >> 4;
  const int bh   = blockIdx.y;
  const int b    = bh >> 4, h = bh & 15;
  const int i0   = blockIdx.x * 64;
  const size_t bb = (size_t)b * S_LEN;

  __shared__ __attribute__((aligned(16))) u16 Ks[32 * 72];
  __shared__ __attribute__((aligned(16))) u16 Vt[64 * 40];
  __shared__ __attribute__((aligned(16))) u16 Ps[4][16 * 40];

  const u16* qrow = qkv + (bb + i0 + 16 * w + m) * 3072 + h * 64;
  const short8 aq0 = *(const short8*)(qrow + quad * 8);
  const short8 aq1 = *(const short8*)(qrow + 32 + quad * 8);

  f32x4 Ov[4];
#pragma unroll
  for (int td = 0; td < 4; ++td) Ov[td] = (f32x4){0.f, 0.f, 0.f, 0.f};
  float mP[4] = {-1e30f, -1e30f, -1e30f, -1e30f};
  float lS[4] = {0.f, 0.f, 0.f, 0.f};

  const int iB = i0 + 16 * w + quad * 4;

  const int lo = max(32, i0 - 128);
  const int hi = min(S_LEN, i0 + 192);
  const int nChunks = 1 + (hi - lo) / 32;

  const int skr = t >> 3;
  const int skc = (t & 7) * 8;

  for (int c = 0; c < nChunks; ++c) {
    const int j0 = (c == 0) ? 0 : lo + (c - 1) * 32;
    __syncthreads();
    {
      const u16* src = qkv + (bb + j0 + skr) * 3072 + 1024 + h * 64 + skc;
      uint4 kk = *(const uint4*)src;
      uint4 vv = *(const uint4*)(src + 1024);
      *(uint4*)&Ks[skr * 72 + skc] = kk;
      const u16 vs[8] = {
        (u16)(vv.x & 0xffffu), (u16)(vv.x >> 16),
        (u16)(vv.y & 0xffffu), (u16)(vv.y >> 16),
        (u16)(vv.z & 0xffffu), (u16)(vv.z >> 16),
        (u16)(vv.w & 0xffffu), (u16)(vv.w >> 16)};
#pragma unroll
      for (int i = 0; i < 8; ++i) Vt[(skc + i) * 40 + skr] = vs[i];
    }
    __syncthreads();

    const short8 b00 = *(const short8*)&Ks[m * 72 + quad * 8];
    const short8 b01 = *(const short8*)&Ks[m * 72 + 32 + quad * 8];
    const short8 b10 = *(const short8*)&Ks[(16 + m) * 72 + quad * 8];
    const short8 b11 = *(const short8*)&Ks[(16 + m) * 72 + 32 + quad * 8];
    f32x4 s0 = (f32x4){0.f, 0.f, 0.f, 0.f};
    f32x4 s1 = (f32x4){0.f, 0.f, 0.f, 0.f};
    s0 = __builtin_amdgcn_mfma_f32_16x16x32_bf16(aq0, b00, s0, 0, 0, 0);
    s0 = __builtin_amdgcn_mfma_f32_16x16x32_bf16(aq1, b01, s0, 0, 0, 0);
    s1 = __builtin_amdgcn_mfma_f32_16x16x32_bf16(aq0, b10, s1, 0, 0, 0);
    s1 = __builtin_amdgcn_mfma_f32_16x16x32_bf16(aq1, b11, s1, 0, 0, 0);

    const int jA = j0 + m, jB = j0 + 16 + m;
#pragma unroll
    for (int r = 0; r < 4; ++r) {
      const int iG = iB + r;
      const int da = iG - jA, db = iG - jB;
      s0[r] = ((jA < 16) || (da >= -128 && da <= 128)) ? s0[r] * 0.125f : -1e30f;
      s1[r] = ((jB < 16) || (db >= -128 && db <= 128)) ? s1[r] * 0.125f : -1e30f;
    }

    float al[4];
#pragma unroll
    for (int r = 0; r < 4; ++r) {
      float mx = fmaxf(s0[r], s1[r]);
      mx = fmaxf(mx, __shfl_xor(mx, 1, 16));
      mx = fmaxf(mx, __shfl_xor(mx, 2, 16));
      mx = fmaxf(mx, __shfl_xor(mx, 4, 16));
      mx = fmaxf(mx, __shfl_xor(mx, 8, 16));
      const float mn = fmaxf(mP[r], mx);
      al[r] = __expf(mP[r] - mn);
      mP[r] = mn;
      const float p0 = __expf(s0[r] - mn);
      const float p1 = __expf(s1[r] - mn);
      float ps = p0 + p1;
      ps += __shfl_xor(ps, 1, 16);
      ps += __shfl_xor(ps, 2, 16);
      ps += __shfl_xor(ps, 4, 16);
      ps += __shfl_xor(ps, 8, 16);
      lS[r] = lS[r] * al[r] + ps;
      Ps[w][(quad * 4 + r) * 40 + m]      = f2bf(p0);
      Ps[w][(quad * 4 + r) * 40 + 16 + m] = f2bf(p1);
    }
#pragma unroll
    for (int td = 0; td < 4; ++td)
#pragma unroll
      for (int r = 0; r < 4; ++r) Ov[td][r] *= al[r];

    const short8 pa = *(const short8*)&Ps[w][m * 40 + quad * 8];
#pragma unroll
    for (int td = 0; td < 4; ++td) {
      const short8 bv = *(const short8*)&Vt[(td * 16 + m) * 40 + quad * 8];
      Ov[td] = __builtin_amdgcn_mfma_f32_16x16x32_bf16(pa, bv, Ov[td], 0, 0, 0);
    }
  }

  if (i0 + 16 * w >= 16) {
    float inv[4];
#pragma unroll
    for (int r = 0; r < 4; ++r) inv[r] = 1.0f / lS[r];
#pragma unroll
    for (int td = 0; td < 4; ++td)
#pragma unroll
      for (int r = 0; r < 4; ++r)
        out[(bb + iB + r) * 1024 + h * 64 + td * 16 + m] =
            f2bf(Ov[td][r] * inv[r]);
  }
}

// ---------------------------------------------------------------------------
// Global rows (i < 16): full attention over all 2048 keys. Block per (b,h,i).
// ---------------------------------------------------------------------------
__global__ __launch_bounds__(256) void attn_global_rows(
    const u16* __restrict__ qkv, u16* __restrict__ out)
{
  const int t  = threadIdx.x;
  const int gi = blockIdx.x;          // 512 = B*H*16
  const int i  = gi & 15;
  const int bh = gi >> 4;
  const int b  = bh >> 4, h = bh & 15;
  __shared__ float Ss[2048];
  __shared__ float qs[64];
  __shared__ float red[4];
  __shared__ float ML[2];
  __shared__ float Opart[4][64];
  const size_t bb = (size_t)b * S_LEN;

  if (t < 64) qs[t] = bf2f(qkv[(bb + i) * 3072 + h * 64 + t]) * 0.125f;
  __syncthreads();

  for (int c = 0; c < 8; ++c) {
    const u16* kr = qkv + (bb + c * 256 + t) * 3072 + 1024 + h * 64;
    float acc = 0.f;
#pragma unroll
    for (int q = 0; q < 8; ++q) {
      uint4 rr = *(const uint4*)(kr + q * 8);
      acc += qs[q * 8 + 0] * bflo(rr.x) + qs[q * 8 + 1] * bfhi(rr.x)
           + qs[q * 8 + 2] * bflo(rr.y) + qs[q * 8 + 3] * bfhi(rr.y)
           + qs[q * 8 + 4] * bflo(rr.z) + qs[q * 8 + 5] * bfhi(rr.z)
           + qs[q * 8 + 6] * bflo(rr.w) + qs[q * 8 + 7] * bfhi(rr.w);
    }
    Ss[c * 256 + t] = acc;
  }
  __syncthreads();

  float m = -1e30f;
#pragma unroll
  for (int c = 0; c < 8; ++c) m = fmaxf(m, Ss[c * 256 + t]);
#pragma unroll
  for (int off = 32; off > 0; off >>= 1) m = fmaxf(m, __shfl_xor(m, off));
  if ((t & 63) == 0) red[t >> 6] = m;
  __syncthreads();
  if (t == 0) ML[0] = fmaxf(fmaxf(red[0], red[1]), fmaxf(red[2], red[3]));
  __syncthreads();
  const float M = ML[0];
  float ls = 0.f;
#pragma unroll
  for (int c = 0; c < 8; ++c) {
    float p = __expf(Ss[c * 256 + t] - M);
    Ss[c * 256 + t] = p;
    ls += p;
  }
#pragma unroll
  for (int off = 32; off > 0; off >>= 1) ls += __shfl_xor(ls, off);
  __syncthreads();
  if ((t & 63) == 0) red[t >> 6] = ls;
  __syncthreads();
  if (t == 0) ML[1] = red[0] + red[1] + red[2] + red[3];
  __syncthreads();
  const float L = ML[1];

  const int d  = t & 63;
  const int qd = t >> 6;
  float oacc = 0.f;
  for (int c = 0; c < 8; ++c) {
#pragma unroll 8
    for (int jl = 0; jl < 64; ++jl) {
      const int j = c * 256 + qd * 64 + jl;
      oacc += Ss[j] * bf2f(qkv[(bb + j) * 3072 + 2048 + h * 64 + d]);
    }
  }
  Opart[qd][d] = oacc;
  __syncthreads();
  if (t < 64) {
    float o = (Opart[0][t] + Opart[1][t] + Opart[2][t] + Opart[3][t]) / L;
    out[(bb + i) * 1024 + h * 64 + t] = f2bf(o);
  }
}

// ---------------------------------------------------------------------------
// Consolidated prep: 6 weight transposes (fp32 -> bf16, out[c][r]=in[r][c])
// + bias concat, one launch. Block ranges:
//   [0,1024)    Wq/Wk/Wv/Wo (each 256 tiles of a 1024x1024)
//   [1024,2048) W1 (R=1024, Cc=4096, tiles (64,16))
//   [2048,3072) W2 (R=4096, Cc=1024, tiles (16,64))
//   [3072,3084) concat bq|bk|bv -> BQKV
// ---------------------------------------------------------------------------
__global__ __launch_bounds__(256) void prep_all(
    const float* __restrict__ Wq, const float* __restrict__ Wk,
    const float* __restrict__ Wv, const float* __restrict__ Wo,
    const float* __restrict__ W1, const float* __restrict__ W2,
    const float* __restrict__ bq, const float* __restrict__ bk,
    const float* __restrict__ bv,
    u16* __restrict__ WQKVT, u16* __restrict__ WOT,
    u16* __restrict__ W1T, u16* __restrict__ W2T,
    float* __restrict__ BQKV)
{
  const int gb = blockIdx.x;
  const int t = threadIdx.x;
  if (gb >= 3072) {  // concat
    const int i = (gb - 3072) * 256 + t;
    if (i < 1024) BQKV[i] = bq[i];
    else if (i < 2048) BQKV[i] = bk[i - 1024];
    else BQKV[i] = bv[i - 2048];
    return;
  }
  const float* in; u16* outp; int R, Cc, bx, by;
  if (gb < 1024) {
    const int seg = gb >> 8, local = gb & 255;
    bx = local & 15; by = local >> 4; R = 1024; Cc = 1024;
    in   = (seg == 0) ? Wq : (seg == 1) ? Wk : (seg == 2) ? Wv : Wo;
    outp = (seg < 3) ? WQKVT + (size_t)seg * 1024 * 1024 : WOT;
  } else if (gb < 2048) {
    const int local = gb - 1024;
    bx = local & 63; by = local >> 6; R = 1024; Cc = 4096;
    in = W1; outp = W1T;
  } else {
    const int local = gb - 2048;
    bx = local & 15; by = local >> 4; R = 4096; Cc = 1024;
    in = W2; outp = W2T;
  }

  __shared__ u16 tile[64][65];
  const int tr = by * 64, tc = bx * 64;
  const int lr = t >> 2, lc0 = (t & 3) * 16;
  const float* src = in + (size_t)(tr + lr) * Cc + tc + lc0;
  float4 a0 = *(const float4*)(src);
  float4 a1 = *(const float4*)(src + 4);
  float4 a2 = *(const float4*)(src + 8);
  float4 a3 = *(const float4*)(src + 12);
  const float vals[16] = {a0.x, a0.y, a0.z, a0.w, a1.x, a1.y, a1.z, a1.w,
                          a2.x, a2.y, a2.z, a2.w, a3.x, a3.y, a3.z, a3.w};
#pragma unroll
  for (int q = 0; q < 16; ++q) tile[lr][lc0 + q] = f2bf(vals[q]);
  __syncthreads();
  u16* dst = outp + (size_t)(tc + lr) * R + tr + lc0;
  u32 w[8];
#pragma unroll
  for (int q = 0; q < 8; ++q)
    w[q] = (u32)tile[lc0 + 2 * q][lr] | ((u32)tile[lc0 + 2 * q + 1][lr] << 16);
  uint4 s0; s0.x = w[0]; s0.y = w[1]; s0.z = w[2]; s0.w = w[3];
  uint4 s1; s1.x = w[4]; s1.y = w[5]; s1.z = w[6]; s1.w = w[7];
  *(uint4*)dst = s0;
  *(uint4*)(dst + 8) = s1;
}

// ---------------------------------------------------------------------------
// workspace layout (bytes) — ~67 MB (unchanged; validated rounds 3-5).
// Partials live in dead regions: Wo partials -> QKV region (dead after
// attention); W2 partials -> W1T + XN (dead after the W1 GEMM).
// ---------------------------------------------------------------------------
static const size_t OFF_WQKVT = 0;                                   // bf16 [3072][1024]
static const size_t OFF_WOT   = OFF_WQKVT + (size_t)3072 * 1024 * 2; // bf16 [1024][1024]
static const size_t OFF_W1T   = OFF_WOT   + (size_t)1024 * 1024 * 2; // bf16 [4096][1024]
static const size_t OFF_W2T   = OFF_W1T   + (size_t)4096 * 1024 * 2; // bf16 [1024][4096]
static const size_t OFF_BQKV  = OFF_W2T   + (size_t)1024 * 4096 * 2; // fp32 [3072]
static const size_t OFF_XN    = OFF_BQKV  + 16384;                   // bf16 [4096][1024]
static const size_t OFF_QKV   = OFF_XN    + (size_t)4096 * 1024 * 2; // bf16 [4096][3072]
static const size_t OFF_AO    = OFF_QKV   + (size_t)4096 * 3072 * 2; // bf16 [4096][1024]
static const size_t OFF_H     = OFF_QKV;  // bf16 [4096][4096], aliases QKV+AO

extern "C" void kernel_launch(void* const* d_in, const int* in_sizes, int n_in,
                              void* d_out, int out_size, void* d_ws, size_t ws_size,
                              hipStream_t stream)
{
  const float* x   = (const float*)d_in[0];
  const float* Wq  = (const float*)d_in[1];
  const float* bq  = (const float*)d_in[2];
  const float* Wk  = (const float*)d_in[3];
  const float* bk  = (const float*)d_in[4];
  const float* Wv  = (const float*)d_in[5];
  const float* bv  = (const float*)d_in[6];
  const float* Wo  = (const float*)d_in[7];
  const float* bo  = (const float*)d_in[8];
  const float* g1  = (const float*)d_in[9];
  const float* be1 = (const float*)d_in[10];
  const float* W1  = (const float*)d_in[11];
  const float* b1  = (const float*)d_in[12];
  const float* W2  = (const float*)d_in[13];
  const float* b2  = (const float*)d_in[14];
  const float* g2  = (const float*)d_in[15];
  const float* be2 = (const float*)d_in[16];
  float* outf = (float*)d_out;
  char* ws = (char*)d_ws;

  u16*   WQKVT = (u16*)(ws + OFF_WQKVT);
  u16*   WOT   = (u16*)(ws + OFF_WOT);
  u16*   W1T   = (u16*)(ws + OFF_W1T);
  u16*   W2T   = (u16*)(ws + OFF_W2T);
  float* BQKV  = (float*)(ws + OFF_BQKV);
  u16*   XN    = (u16*)(ws + OFF_XN);
  u16*   QKV   = (u16*)(ws + OFF_QKV);
  u16*   AO    = (u16*)(ws + OFF_AO);
  u16*   Hbuf  = (u16*)(ws + OFF_H);
  float* X1    = outf;  // fp32 residual stream #2 lives in d_out
  // split-K partial buffers (bf16 [4096][1024] each)
  u16* PWo0 = (u16*)(ws + OFF_QKV);                       // QKV region (dead)
  u16* PWo1 = PWo0 + (size_t)4096 * 1024;
  u16* PW20 = (u16*)(ws + OFF_W1T);                       // W1T (dead after W1)
  u16* PW21 = (u16*)(ws + OFF_XN);                        // XN  (dead after W1)

  const dim3 blk(256);
  prep_all<<<dim3(3084), blk, 0, stream>>>(Wq, Wk, Wv, Wo, W1, W2, bq, bk, bv,
                                           WQKVT, WOT, W1T, W2T, BQKV);

  // attention sublayer
  ln_kernel<<<dim3(ROWS), blk, 0, stream>>>(x, g1, be1, XN);
  gemm_bt<0, 0><<<dim3(24, 32), blk, 0, stream>>>(XN, WQKVT, BQKV, nullptr,
                                                  QKV, nullptr, ROWS, 3072, 1024);
  attn_band<<<dim3(32, 32), blk, 0, stream>>>(QKV, AO);
  attn_global_rows<<<dim3(512), blk, 0, stream>>>(QKV, AO);
  gemm_sp<<<dim3(8, 32, 2), blk, 0, stream>>>(AO, WOT, PWo0, PWo1,
                                              ROWS, 1024, 1024, 512);
  reduce2<<<dim3(2048), blk, 0, stream>>>(PWo0, PWo1, bo, x, X1);

  // FFN sublayer
  ln_kernel<<<dim3(ROWS), blk, 0, stream>>>(X1, g2, be2, XN);
  gemm_bt<1, 0><<<dim3(32, 32), blk, 0, stream>>>(XN, W1T, b1, nullptr,
                                                  Hbuf, nullptr, ROWS, 4096, 1024);
  gemm_sp<<<dim3(8, 32, 2), blk, 0, stream>>>(Hbuf, W2T, PW20, PW21,
                                              ROWS, 1024, 4096, 2048);
  reduce2<<<dim3(2048), blk, 0, stream>>>(PW20, PW21, b2, X1, outf);
}

// Round 7
// 429.016 us; speedup vs baseline: 1.4387x; 1.0688x over previous
//
#include <hip/hip_runtime.h>
#include <stdint.h>

// ---------------------------------------------------------------------------
// EncoderBlock: pre-norm transformer block, MI355X (gfx950).
// External dtype: FP32. Internal: bf16 MFMA, fp32 accum, fp32 residual.
// B=2 S=2048 D=1024 H=16 DK=64 DFF=4096 WINDOW=128 GLOBAL=16
// ---------------------------------------------------------------------------

typedef unsigned short u16;
typedef unsigned int   u32;
typedef __attribute__((ext_vector_type(8))) short  short8;  // 8 bf16 (4 VGPRs)
typedef __attribute__((ext_vector_type(4))) float  f32x4;

#define S_LEN   2048
#define D_MODEL 1024
#define ROWS    4096   // B*S

__device__ __forceinline__ float bf2f(u16 u) {
  union { u32 i; float f; } v; v.i = ((u32)u) << 16; return v.f;
}
__device__ __forceinline__ float bflo(u32 u) {
  union { u32 i; float f; } v; v.i = u << 16; return v.f;
}
__device__ __forceinline__ float bfhi(u32 u) {
  union { u32 i; float f; } v; v.i = u & 0xffff0000u; return v.f;
}
__device__ __forceinline__ u16 f2bf(float f) {
  union { float f; u32 i; } v; v.f = f;
  u32 r = v.i + 0x7fffu + ((v.i >> 16) & 1u);
  return (u16)(r >> 16);
}

// Direct global->LDS copy, 16B/lane (m97). Lands at wave base + lane*16.
__device__ __forceinline__ void gld_lds16(const u16* g, u16* l) {
  __attribute__((address_space(3))) u32* lp =
      reinterpret_cast<__attribute__((address_space(3))) u32*>(
          reinterpret_cast<uintptr_t>(l));
  const __attribute__((address_space(1))) u32* gp =
      reinterpret_cast<const __attribute__((address_space(1))) u32*>(
          reinterpret_cast<uintptr_t>(g));
  __builtin_amdgcn_global_load_lds(gp, lp, 16, 0, 0);
}

// k-chunk swizzle (round-5 verified: SQ_LDS_BANK_CONFLICT 4.19M -> 0):
// LDS slot s at row R holds global k-chunk (s-(R>>1))&3; reader of chunk kq
// uses slot (kq+(R>>1))&3. Swizzle applied on the GLOBAL address at staging.

// ---------------------------------------------------------------------------
// GEMM 128x128, double-buffered LDS, ONE barrier per K-iter.
// Round-6 diagnosis: the 2-barrier loop issued loads then immediately
// drained vmcnt(0) at the barrier -> full load latency exposed each iter at
// ~2 blocks/CU (MfmaUtil 12%, ~300 TF). Here the prefetch for k+1 issues
// right after the barrier and drains only at the NEXT barrier, i.e. after a
// full compute section covers it.
// EPI: 0=bias, 1=bias+gelu. OUTF: 0=bf16, 1=fp32 out.
// ---------------------------------------------------------------------------
template <int EPI, int OUTF>
__global__ __launch_bounds__(256) void gemm_bt(
    const u16* __restrict__ A, const u16* __restrict__ Bt,
    const float* __restrict__ bias, const float* res,
    u16* Cb, float* Cf, int M, int N, int K)
{
  __shared__ __attribute__((aligned(16))) u16 As[2][128 * 32];
  __shared__ __attribute__((aligned(16))) u16 Bs[2][128 * 32];
  const int tid  = threadIdx.x;
  const int wave = tid >> 6;
  const int lane = tid & 63;
  const int bm = blockIdx.y * 128;
  const int bn = blockIdx.x * 128;
  const int wr = (wave >> 1) * 64;
  const int wc = (wave & 1) * 64;
  const int lm = lane & 15;
  const int kq = lane >> 4;

  f32x4 acc[4][4];
#pragma unroll
  for (int i = 0; i < 4; ++i)
#pragma unroll
    for (int j = 0; j < 4; ++j) acc[i][j] = (f32x4){0.f, 0.f, 0.f, 0.f};

  const int srow = wave * 16 + (lane >> 2);
  const int kg   = (((lane & 3) - (srow >> 1)) & 3) * 8;
  const u16* gA = A  + (size_t)(bm + srow) * K + kg;
  const u16* gB = Bt + (size_t)(bn + srow) * K + kg;
  const int wb = (wave * 16) * 32;

  // prologue: stage k=0 into buffer 0
  gld_lds16(gA, &As[0][wb]);
  gld_lds16(gA + (size_t)64 * K, &As[0][wb + 64 * 32]);
  gld_lds16(gB, &Bs[0][wb]);
  gld_lds16(gB + (size_t)64 * K, &Bs[0][wb + 64 * 32]);

  int buf = 0;
  for (int k0 = 0; k0 < K; k0 += 32, buf ^= 1) {
    __syncthreads();  // drains this wave's prefetch (issued last iter) + syncs
    const int kn = k0 + 32;
    if (kn < K) {     // prefetch k+1 into the other buffer (drains NEXT iter)
      gld_lds16(gA + kn, &As[buf ^ 1][wb]);
      gld_lds16(gA + (size_t)64 * K + kn, &As[buf ^ 1][wb + 64 * 32]);
      gld_lds16(gB + kn, &Bs[buf ^ 1][wb]);
      gld_lds16(gB + (size_t)64 * K + kn, &Bs[buf ^ 1][wb + 64 * 32]);
    }

    short8 af[4], bfv[4];
#pragma unroll
    for (int ti = 0; ti < 4; ++ti) {
      const int Ra = wr + ti * 16 + lm;
      af[ti] = *(const short8*)&As[buf][Ra * 32 + (((kq + (Ra >> 1)) & 3) * 8)];
    }
#pragma unroll
    for (int tj = 0; tj < 4; ++tj) {
      const int Rb = wc + tj * 16 + lm;
      bfv[tj] = *(const short8*)&Bs[buf][Rb * 32 + (((kq + (Rb >> 1)) & 3) * 8)];
    }
#pragma unroll
    for (int ti = 0; ti < 4; ++ti)
#pragma unroll
      for (int tj = 0; tj < 4; ++tj)
        acc[ti][tj] = __builtin_amdgcn_mfma_f32_16x16x32_bf16(
            af[ti], bfv[tj], acc[ti][tj], 0, 0, 0);
  }

  const int r0 = (lane >> 4) * 4;
#pragma unroll
  for (int ti = 0; ti < 4; ++ti) {
#pragma unroll
    for (int r = 0; r < 4; ++r) {
      const int grow = bm + wr + ti * 16 + r0 + r;
#pragma unroll
      for (int tj = 0; tj < 4; ++tj) {
        const int gcol = bn + wc + tj * 16 + lm;
        const size_t idx = (size_t)grow * N + gcol;
        float v = acc[ti][tj][r] + bias[gcol];
        if (EPI == 1) v = 0.5f * v * (1.0f + erff(v * 0.70710678118654752f));
        if (OUTF) Cf[idx] = v;
        else      Cb[idx] = f2bf(v);
      }
    }
  }
}

// ---------------------------------------------------------------------------
// Split-K GEMM (Wo/W2: N=1024), same double-buffered structure. Grid
// (N/128, M/128, 2) = 512 blocks. Partials bf16 -> reduce2.
// ---------------------------------------------------------------------------
__global__ __launch_bounds__(256) void gemm_sp(
    const u16* __restrict__ A, const u16* __restrict__ Bt,
    u16* __restrict__ P0, u16* __restrict__ P1,
    int M, int N, int K, int KH)
{
  __shared__ __attribute__((aligned(16))) u16 As[2][128 * 32];
  __shared__ __attribute__((aligned(16))) u16 Bs[2][128 * 32];
  const int tid  = threadIdx.x;
  const int wave = tid >> 6;
  const int lane = tid & 63;
  const int bm = blockIdx.y * 128;
  const int bn = blockIdx.x * 128;
  const int kz = blockIdx.z;
  u16* P = kz ? P1 : P0;
  const int wr = (wave >> 1) * 64;
  const int wc = (wave & 1) * 64;
  const int lm = lane & 15;
  const int kq = lane >> 4;

  f32x4 acc[4][4];
#pragma unroll
  for (int i = 0; i < 4; ++i)
#pragma unroll
    for (int j = 0; j < 4; ++j) acc[i][j] = (f32x4){0.f, 0.f, 0.f, 0.f};

  const int srow = wave * 16 + (lane >> 2);
  const int kg   = (((lane & 3) - (srow >> 1)) & 3) * 8;
  const u16* gA = A  + (size_t)(bm + srow) * K + kz * KH + kg;
  const u16* gB = Bt + (size_t)(bn + srow) * K + kz * KH + kg;
  const int wb = (wave * 16) * 32;

  gld_lds16(gA, &As[0][wb]);
  gld_lds16(gA + (size_t)64 * K, &As[0][wb + 64 * 32]);
  gld_lds16(gB, &Bs[0][wb]);
  gld_lds16(gB + (size_t)64 * K, &Bs[0][wb + 64 * 32]);

  int buf = 0;
  for (int k0 = 0; k0 < KH; k0 += 32, buf ^= 1) {
    __syncthreads();
    const int kn = k0 + 32;
    if (kn < KH) {
      gld_lds16(gA + kn, &As[buf ^ 1][wb]);
      gld_lds16(gA + (size_t)64 * K + kn, &As[buf ^ 1][wb + 64 * 32]);
      gld_lds16(gB + kn, &Bs[buf ^ 1][wb]);
      gld_lds16(gB + (size_t)64 * K + kn, &Bs[buf ^ 1][wb + 64 * 32]);
    }

    short8 af[4], bfv[4];
#pragma unroll
    for (int ti = 0; ti < 4; ++ti) {
      const int Ra = wr + ti * 16 + lm;
      af[ti] = *(const short8*)&As[buf][Ra * 32 + (((kq + (Ra >> 1)) & 3) * 8)];
    }
#pragma unroll
    for (int tj = 0; tj < 4; ++tj) {
      const int Rb = wc + tj * 16 + lm;
      bfv[tj] = *(const short8*)&Bs[buf][Rb * 32 + (((kq + (Rb >> 1)) & 3) * 8)];
    }
#pragma unroll
    for (int ti = 0; ti < 4; ++ti)
#pragma unroll
      for (int tj = 0; tj < 4; ++tj)
        acc[ti][tj] = __builtin_amdgcn_mfma_f32_16x16x32_bf16(
            af[ti], bfv[tj], acc[ti][tj], 0, 0, 0);
  }

  const int r0 = (lane >> 4) * 4;
#pragma unroll
  for (int ti = 0; ti < 4; ++ti) {
#pragma unroll
    for (int r = 0; r < 4; ++r) {
      const int grow = bm + wr + ti * 16 + r0 + r;
#pragma unroll
      for (int tj = 0; tj < 4; ++tj) {
        const int gcol = bn + wc + tj * 16 + lm;
        P[(size_t)grow * N + gcol] = f2bf(acc[ti][tj][r]);
      }
    }
  }
}

// out[idx] = P0[idx] + P1[idx] + bias[col] + res[idx]   (N fixed = 1024)
__global__ __launch_bounds__(256) void reduce2(
    const u16* __restrict__ P0, const u16* __restrict__ P1,
    const float* __restrict__ bias, const float* res, float* out)
{
  const size_t base = ((size_t)blockIdx.x * 256 + threadIdx.x) * 8;
  const int col = (int)(base & 1023);
  uint4 p0 = *(const uint4*)(P0 + base);
  uint4 p1 = *(const uint4*)(P1 + base);
  float4 b0 = *(const float4*)(bias + col);
  float4 b1 = *(const float4*)(bias + col + 4);
  float4 r0 = *(const float4*)(res + base);
  float4 r1 = *(const float4*)(res + base + 4);
  float4 o0, o1;
  o0.x = bflo(p0.x) + bflo(p1.x) + b0.x + r0.x;
  o0.y = bfhi(p0.x) + bfhi(p1.x) + b0.y + r0.y;
  o0.z = bflo(p0.y) + bflo(p1.y) + b0.z + r0.z;
  o0.w = bfhi(p0.y) + bfhi(p1.y) + b0.w + r0.w;
  o1.x = bflo(p0.z) + bflo(p1.z) + b1.x + r1.x;
  o1.y = bfhi(p0.z) + bfhi(p1.z) + b1.y + r1.y;
  o1.z = bflo(p0.w) + bflo(p1.w) + b1.z + r1.z;
  o1.w = bfhi(p0.w) + bfhi(p1.w) + b1.w + r1.w;
  *(float4*)(out + base) = o0;
  *(float4*)(out + base + 4) = o1;
}

// ---------------------------------------------------------------------------
// LayerNorm: fp32 in, bf16 out. One block per row (D=1024).
// ---------------------------------------------------------------------------
__global__ __launch_bounds__(256) void ln_kernel(
    const float* __restrict__ x, const float* __restrict__ g,
    const float* __restrict__ b, u16* __restrict__ o)
{
  const int row = blockIdx.x;
  const int t = threadIdx.x;
  float4 v = *(const float4*)(x + (size_t)row * D_MODEL + t * 4);
  float s  = v.x + v.y + v.z + v.w;
  float ss = v.x * v.x + v.y * v.y + v.z * v.z + v.w * v.w;
#pragma unroll
  for (int off = 32; off > 0; off >>= 1) {
    s  += __shfl_down(s, off);
    ss += __shfl_down(ss, off);
  }
  __shared__ float sm[4], ssm[4], stat[2];
  if ((t & 63) == 0) { sm[t >> 6] = s; ssm[t >> 6] = ss; }
  __syncthreads();
  if (t == 0) {
    float S = sm[0] + sm[1] + sm[2] + sm[3];
    float SS = ssm[0] + ssm[1] + ssm[2] + ssm[3];
    float mu = S * (1.0f / 1024.0f);
    float var = SS * (1.0f / 1024.0f) - mu * mu;
    stat[0] = mu;
    stat[1] = rsqrtf(fmaxf(var, 0.0f) + 1e-5f);
  }
  __syncthreads();
  const float mu = stat[0], rstd = stat[1];
  float4 gg = *(const float4*)(g + t * 4);
  float4 bb = *(const float4*)(b + t * 4);
  u16 o0 = f2bf((v.x - mu) * rstd * gg.x + bb.x);
  u16 o1 = f2bf((v.y - mu) * rstd * gg.y + bb.y);
  u16 o2 = f2bf((v.z - mu) * rstd * gg.z + bb.z);
  u16 o3 = f2bf((v.w - mu) * rstd * gg.w + bb.w);
  uint2 w;
  w.x = (u32)o0 | ((u32)o1 << 16);
  w.y = (u32)o2 | ((u32)o3 << 16);
  *(uint2*)(o + (size_t)row * D_MODEL + t * 4) = w;
}

// ---------------------------------------------------------------------------
// Banded attention, MFMA flash style (rounds 4-6 verified).
// ---------------------------------------------------------------------------
__global__ __launch_bounds__(256) void attn_band(
    const u16* __restrict__ qkv, u16* __restrict__ out)
{
  const int t    = threadIdx.x;
  const int w    = t >> 6;
  const int lane = t & 63;
  const int m    = lane & 15;
  const int quad = lane >> 4;
  const int bh   = blockIdx.y;
  const int b    = bh >> 4, h = bh & 15;
  const int i0   = blockIdx.x * 64;
  const size_t bb = (size_t)b * S_LEN;

  __shared__ __attribute__((aligned(16))) u16 Ks[32 * 72];
  __shared__ __attribute__((aligned(16))) u16 Vt[64 * 40];
  __shared__ __attribute__((aligned(16))) u16 Ps[4][16 * 40];

  const u16* qrow = qkv + (bb + i0 + 16 * w + m) * 3072 + h * 64;
  const short8 aq0 = *(const short8*)(qrow + quad * 8);
  const short8 aq1 = *(const short8*)(qrow + 32 + quad * 8);

  f32x4 Ov[4];
#pragma unroll
  for (int td = 0; td < 4; ++td) Ov[td] = (f32x4){0.f, 0.f, 0.f, 0.f};
  float mP[4] = {-1e30f, -1e30f, -1e30f, -1e30f};
  float lS[4] = {0.f, 0.f, 0.f, 0.f};

  const int iB = i0 + 16 * w + quad * 4;

  const int lo = max(32, i0 - 128);
  const int hi = min(S_LEN, i0 + 192);
  const int nChunks = 1 + (hi - lo) / 32;

  const int skr = t >> 3;
  const int skc = (t & 7) * 8;

  for (int c = 0; c < nChunks; ++c) {
    const int j0 = (c == 0) ? 0 : lo + (c - 1) * 32;
    __syncthreads();
    {
      const u16* src = qkv + (bb + j0 + skr) * 3072 + 1024 + h * 64 + skc;
      uint4 kk = *(const uint4*)src;
      uint4 vv = *(const uint4*)(src + 1024);
      *(uint4*)&Ks[skr * 72 + skc] = kk;
      const u16 vs[8] = {
        (u16)(vv.x & 0xffffu), (u16)(vv.x >> 16),
        (u16)(vv.y & 0xffffu), (u16)(vv.y >> 16),
        (u16)(vv.z & 0xffffu), (u16)(vv.z >> 16),
        (u16)(vv.w & 0xffffu), (u16)(vv.w >> 16)};
#pragma unroll
      for (int i = 0; i < 8; ++i) Vt[(skc + i) * 40 + skr] = vs[i];
    }
    __syncthreads();

    const short8 b00 = *(const short8*)&Ks[m * 72 + quad * 8];
    const short8 b01 = *(const short8*)&Ks[m * 72 + 32 + quad * 8];
    const short8 b10 = *(const short8*)&Ks[(16 + m) * 72 + quad * 8];
    const short8 b11 = *(const short8*)&Ks[(16 + m) * 72 + 32 + quad * 8];
    f32x4 s0 = (f32x4){0.f, 0.f, 0.f, 0.f};
    f32x4 s1 = (f32x4){0.f, 0.f, 0.f, 0.f};
    s0 = __builtin_amdgcn_mfma_f32_16x16x32_bf16(aq0, b00, s0, 0, 0, 0);
    s0 = __builtin_amdgcn_mfma_f32_16x16x32_bf16(aq1, b01, s0, 0, 0, 0);
    s1 = __builtin_amdgcn_mfma_f32_16x16x32_bf16(aq0, b10, s1, 0, 0, 0);
    s1 = __builtin_amdgcn_mfma_f32_16x16x32_bf16(aq1, b11, s1, 0, 0, 0);

    const int jA = j0 + m, jB = j0 + 16 + m;
#pragma unroll
    for (int r = 0; r < 4; ++r) {
      const int iG = iB + r;
      const int da = iG - jA, db = iG - jB;
      s0[r] = ((jA < 16) || (da >= -128 && da <= 128)) ? s0[r] * 0.125f : -1e30f;
      s1[r] = ((jB < 16) || (db >= -128 && db <= 128)) ? s1[r] * 0.125f : -1e30f;
    }

    float al[4];
#pragma unroll
    for (int r = 0; r < 4; ++r) {
      float mx = fmaxf(s0[r], s1[r]);
      mx = fmaxf(mx, __shfl_xor(mx, 1, 16));
      mx = fmaxf(mx, __shfl_xor(mx, 2, 16));
      mx = fmaxf(mx, __shfl_xor(mx, 4, 16));
      mx = fmaxf(mx, __shfl_xor(mx, 8, 16));
      const float mn = fmaxf(mP[r], mx);
      al[r] = __expf(mP[r] - mn);
      mP[r] = mn;
      const float p0 = __expf(s0[r] - mn);
      const float p1 = __expf(s1[r] - mn);
      float ps = p0 + p1;
      ps += __shfl_xor(ps, 1, 16);
      ps += __shfl_xor(ps, 2, 16);
      ps += __shfl_xor(ps, 4, 16);
      ps += __shfl_xor(ps, 8, 16);
      lS[r] = lS[r] * al[r] + ps;
      Ps[w][(quad * 4 + r) * 40 + m]      = f2bf(p0);
      Ps[w][(quad * 4 + r) * 40 + 16 + m] = f2bf(p1);
    }
#pragma unroll
    for (int td = 0; td < 4; ++td)
#pragma unroll
      for (int r = 0; r < 4; ++r) Ov[td][r] *= al[r];

    const short8 pa = *(const short8*)&Ps[w][m * 40 + quad * 8];
#pragma unroll
    for (int td = 0; td < 4; ++td) {
      const short8 bv = *(const short8*)&Vt[(td * 16 + m) * 40 + quad * 8];
      Ov[td] = __builtin_amdgcn_mfma_f32_16x16x32_bf16(pa, bv, Ov[td], 0, 0, 0);
    }
  }

  if (i0 + 16 * w >= 16) {
    float inv[4];
#pragma unroll
    for (int r = 0; r < 4; ++r) inv[r] = 1.0f / lS[r];
#pragma unroll
    for (int td = 0; td < 4; ++td)
#pragma unroll
      for (int r = 0; r < 4; ++r)
        out[(bb + iB + r) * 1024 + h * 64 + td * 16 + m] =
            f2bf(Ov[td][r] * inv[r]);
  }
}

// ---------------------------------------------------------------------------
// Global rows (i < 16): full attention over all 2048 keys. Block per (b,h,i).
// ---------------------------------------------------------------------------
__global__ __launch_bounds__(256) void attn_global_rows(
    const u16* __restrict__ qkv, u16* __restrict__ out)
{
  const int t  = threadIdx.x;
  const int gi = blockIdx.x;          // 512 = B*H*16
  const int i  = gi & 15;
  const int bh = gi >> 4;
  const int b  = bh >> 4, h = bh & 15;
  __shared__ float Ss[2048];
  __shared__ float qs[64];
  __shared__ float red[4];
  __shared__ float ML[2];
  __shared__ float Opart[4][64];
  const size_t bb = (size_t)b * S_LEN;

  if (t < 64) qs[t] = bf2f(qkv[(bb + i) * 3072 + h * 64 + t]) * 0.125f;
  __syncthreads();

  for (int c = 0; c < 8; ++c) {
    const u16* kr = qkv + (bb + c * 256 + t) * 3072 + 1024 + h * 64;
    float acc = 0.f;
#pragma unroll
    for (int q = 0; q < 8; ++q) {
      uint4 rr = *(const uint4*)(kr + q * 8);
      acc += qs[q * 8 + 0] * bflo(rr.x) + qs[q * 8 + 1] * bfhi(rr.x)
           + qs[q * 8 + 2] * bflo(rr.y) + qs[q * 8 + 3] * bfhi(rr.y)
           + qs[q * 8 + 4] * bflo(rr.z) + qs[q * 8 + 5] * bfhi(rr.z)
           + qs[q * 8 + 6] * bflo(rr.w) + qs[q * 8 + 7] * bfhi(rr.w);
    }
    Ss[c * 256 + t] = acc;
  }
  __syncthreads();

  float m = -1e30f;
#pragma unroll
  for (int c = 0; c < 8; ++c) m = fmaxf(m, Ss[c * 256 + t]);
#pragma unroll
  for (int off = 32; off > 0; off >>= 1) m = fmaxf(m, __shfl_xor(m, off));
  if ((t & 63) == 0) red[t >> 6] = m;
  __syncthreads();
  if (t == 0) ML[0] = fmaxf(fmaxf(red[0], red[1]), fmaxf(red[2], red[3]));
  __syncthreads();
  const float M = ML[0];
  float ls = 0.f;
#pragma unroll
  for (int c = 0; c < 8; ++c) {
    float p = __expf(Ss[c * 256 + t] - M);
    Ss[c * 256 + t] = p;
    ls += p;
  }
#pragma unroll
  for (int off = 32; off > 0; off >>= 1) ls += __shfl_xor(ls, off);
  __syncthreads();
  if ((t & 63) == 0) red[t >> 6] = ls;
  __syncthreads();
  if (t == 0) ML[1] = red[0] + red[1] + red[2] + red[3];
  __syncthreads();
  const float L = ML[1];

  const int d  = t & 63;
  const int qd = t >> 6;
  float oacc = 0.f;
  for (int c = 0; c < 8; ++c) {
#pragma unroll 8
    for (int jl = 0; jl < 64; ++jl) {
      const int j = c * 256 + qd * 64 + jl;
      oacc += Ss[j] * bf2f(qkv[(bb + j) * 3072 + 2048 + h * 64 + d]);
    }
  }
  Opart[qd][d] = oacc;
  __syncthreads();
  if (t < 64) {
    float o = (Opart[0][t] + Opart[1][t] + Opart[2][t] + Opart[3][t]) / L;
    out[(bb + i) * 1024 + h * 64 + t] = f2bf(o);
  }
}

// ---------------------------------------------------------------------------
// Consolidated prep: 6 weight transposes (fp32 -> bf16) + bias concat.
// ---------------------------------------------------------------------------
__global__ __launch_bounds__(256) void prep_all(
    const float* __restrict__ Wq, const float* __restrict__ Wk,
    const float* __restrict__ Wv, const float* __restrict__ Wo,
    const float* __restrict__ W1, const float* __restrict__ W2,
    const float* __restrict__ bq, const float* __restrict__ bk,
    const float* __restrict__ bv,
    u16* __restrict__ WQKVT, u16* __restrict__ WOT,
    u16* __restrict__ W1T, u16* __restrict__ W2T,
    float* __restrict__ BQKV)
{
  const int gb = blockIdx.x;
  const int t = threadIdx.x;
  if (gb >= 3072) {  // concat
    const int i = (gb - 3072) * 256 + t;
    if (i < 1024) BQKV[i] = bq[i];
    else if (i < 2048) BQKV[i] = bk[i - 1024];
    else BQKV[i] = bv[i - 2048];
    return;
  }
  const float* in; u16* outp; int R, Cc, bx, by;
  if (gb < 1024) {
    const int seg = gb >> 8, local = gb & 255;
    bx = local & 15; by = local >> 4; R = 1024; Cc = 1024;
    in   = (seg == 0) ? Wq : (seg == 1) ? Wk : (seg == 2) ? Wv : Wo;
    outp = (seg < 3) ? WQKVT + (size_t)seg * 1024 * 1024 : WOT;
  } else if (gb < 2048) {
    const int local = gb - 1024;
    bx = local & 63; by = local >> 6; R = 1024; Cc = 4096;
    in = W1; outp = W1T;
  } else {
    const int local = gb - 2048;
    bx = local & 15; by = local >> 4; R = 4096; Cc = 1024;
    in = W2; outp = W2T;
  }

  __shared__ u16 tile[64][65];
  const int tr = by * 64, tc = bx * 64;
  const int lr = t >> 2, lc0 = (t & 3) * 16;
  const float* src = in + (size_t)(tr + lr) * Cc + tc + lc0;
  float4 a0 = *(const float4*)(src);
  float4 a1 = *(const float4*)(src + 4);
  float4 a2 = *(const float4*)(src + 8);
  float4 a3 = *(const float4*)(src + 12);
  const float vals[16] = {a0.x, a0.y, a0.z, a0.w, a1.x, a1.y, a1.z, a1.w,
                          a2.x, a2.y, a2.z, a2.w, a3.x, a3.y, a3.z, a3.w};
#pragma unroll
  for (int q = 0; q < 16; ++q) tile[lr][lc0 + q] = f2bf(vals[q]);
  __syncthreads();
  u16* dst = outp + (size_t)(tc + lr) * R + tr + lc0;
  u32 w[8];
#pragma unroll
  for (int q = 0; q < 8; ++q)
    w[q] = (u32)tile[lc0 + 2 * q][lr] | ((u32)tile[lc0 + 2 * q + 1][lr] << 16);
  uint4 s0; s0.x = w[0]; s0.y = w[1]; s0.z = w[2]; s0.w = w[3];
  uint4 s1; s1.x = w[4]; s1.y = w[5]; s1.z = w[6]; s1.w = w[7];
  *(uint4*)dst = s0;
  *(uint4*)(dst + 8) = s1;
}

// ---------------------------------------------------------------------------
// workspace layout (bytes) — ~67 MB (validated rounds 3-6). Split-K partials
// in dead regions: Wo -> QKV region; W2 -> W1T + XN (dead after W1).
// ---------------------------------------------------------------------------
static const size_t OFF_WQKVT = 0;                                   // bf16 [3072][1024]
static const size_t OFF_WOT   = OFF_WQKVT + (size_t)3072 * 1024 * 2; // bf16 [1024][1024]
static const size_t OFF_W1T   = OFF_WOT   + (size_t)1024 * 1024 * 2; // bf16 [4096][1024]
static const size_t OFF_W2T   = OFF_W1T   + (size_t)4096 * 1024 * 2; // bf16 [1024][4096]
static const size_t OFF_BQKV  = OFF_W2T   + (size_t)1024 * 4096 * 2; // fp32 [3072]
static const size_t OFF_XN    = OFF_BQKV  + 16384;                   // bf16 [4096][1024]
static const size_t OFF_QKV   = OFF_XN    + (size_t)4096 * 1024 * 2; // bf16 [4096][3072]
static const size_t OFF_AO    = OFF_QKV   + (size_t)4096 * 3072 * 2; // bf16 [4096][1024]
static const size_t OFF_H     = OFF_QKV;  // bf16 [4096][4096], aliases QKV+AO

extern "C" void kernel_launch(void* const* d_in, const int* in_sizes, int n_in,
                              void* d_out, int out_size, void* d_ws, size_t ws_size,
                              hipStream_t stream)
{
  const float* x   = (const float*)d_in[0];
  const float* Wq  = (const float*)d_in[1];
  const float* bq  = (const float*)d_in[2];
  const float* Wk  = (const float*)d_in[3];
  const float* bk  = (const float*)d_in[4];
  const float* Wv  = (const float*)d_in[5];
  const float* bv  = (const float*)d_in[6];
  const float* Wo  = (const float*)d_in[7];
  const float* bo  = (const float*)d_in[8];
  const float* g1  = (const float*)d_in[9];
  const float* be1 = (const float*)d_in[10];
  const float* W1  = (const float*)d_in[11];
  const float* b1  = (const float*)d_in[12];
  const float* W2  = (const float*)d_in[13];
  const float* b2  = (const float*)d_in[14];
  const float* g2  = (const float*)d_in[15];
  const float* be2 = (const float*)d_in[16];
  float* outf = (float*)d_out;
  char* ws = (char*)d_ws;

  u16*   WQKVT = (u16*)(ws + OFF_WQKVT);
  u16*   WOT   = (u16*)(ws + OFF_WOT);
  u16*   W1T   = (u16*)(ws + OFF_W1T);
  u16*   W2T   = (u16*)(ws + OFF_W2T);
  float* BQKV  = (float*)(ws + OFF_BQKV);
  u16*   XN    = (u16*)(ws + OFF_XN);
  u16*   QKV   = (u16*)(ws + OFF_QKV);
  u16*   AO    = (u16*)(ws + OFF_AO);
  u16*   Hbuf  = (u16*)(ws + OFF_H);
  float* X1    = outf;  // fp32 residual stream #2 lives in d_out
  u16* PWo0 = (u16*)(ws + OFF_QKV);
  u16* PWo1 = PWo0 + (size_t)4096 * 1024;
  u16* PW20 = (u16*)(ws + OFF_W1T);
  u16* PW21 = (u16*)(ws + OFF_XN);

  const dim3 blk(256);
  prep_all<<<dim3(3084), blk, 0, stream>>>(Wq, Wk, Wv, Wo, W1, W2, bq, bk, bv,
                                           WQKVT, WOT, W1T, W2T, BQKV);

  // attention sublayer
  ln_kernel<<<dim3(ROWS), blk, 0, stream>>>(x, g1, be1, XN);
  gemm_bt<0, 0><<<dim3(24, 32), blk, 0, stream>>>(XN, WQKVT, BQKV, nullptr,
                                                  QKV, nullptr, ROWS, 3072, 1024);
  attn_band<<<dim3(32, 32), blk, 0, stream>>>(QKV, AO);
  attn_global_rows<<<dim3(512), blk, 0, stream>>>(QKV, AO);
  gemm_sp<<<dim3(8, 32, 2), blk, 0, stream>>>(AO, WOT, PWo0, PWo1,
                                              ROWS, 1024, 1024, 512);
  reduce2<<<dim3(2048), blk, 0, stream>>>(PWo0, PWo1, bo, x, X1);

  // FFN sublayer
  ln_kernel<<<dim3(ROWS), blk, 0, stream>>>(X1, g2, be2, XN);
  gemm_bt<1, 0><<<dim3(32, 32), blk, 0, stream>>>(XN, W1T, b1, nullptr,
                                                  Hbuf, nullptr, ROWS, 4096, 1024);
  gemm_sp<<<dim3(8, 32, 2), blk, 0, stream>>>(Hbuf, W2T, PW20, PW21,
                                              ROWS, 1024, 4096, 2048);
  reduce2<<<dim3(2048), blk, 0, stream>>>(PW20, PW21, b2, X1, outf);
}

// Round 8
// 366.983 us; speedup vs baseline: 1.6819x; 1.1690x over previous
//
#include <hip/hip_runtime.h>
#include <stdint.h>

// ---------------------------------------------------------------------------
// EncoderBlock: pre-norm transformer block, MI355X (gfx950).
// External dtype: FP32. Internal: bf16 MFMA, fp32 accum, fp32 residual.
// B=2 S=2048 D=1024 H=16 DK=64 DFF=4096 WINDOW=128 GLOBAL=16
// ---------------------------------------------------------------------------

typedef unsigned short u16;
typedef unsigned int   u32;
typedef __attribute__((ext_vector_type(8))) short  short8;  // 8 bf16 (4 VGPRs)
typedef __attribute__((ext_vector_type(4))) float  f32x4;

#define S_LEN   2048
#define D_MODEL 1024
#define ROWS    4096   // B*S

__device__ __forceinline__ float bf2f(u16 u) {
  union { u32 i; float f; } v; v.i = ((u32)u) << 16; return v.f;
}
__device__ __forceinline__ float bflo(u32 u) {
  union { u32 i; float f; } v; v.i = u << 16; return v.f;
}
__device__ __forceinline__ float bfhi(u32 u) {
  union { u32 i; float f; } v; v.i = u & 0xffff0000u; return v.f;
}
__device__ __forceinline__ u16 f2bf(float f) {
  union { float f; u32 i; } v; v.f = f;
  u32 r = v.i + 0x7fffu + ((v.i >> 16) & 1u);
  return (u16)(r >> 16);
}

// Direct global->LDS copy, 16B/lane (m97). Lands at wave base + lane*16.
__device__ __forceinline__ void gld_lds16(const u16* g, u16* l) {
  __attribute__((address_space(3))) u32* lp =
      reinterpret_cast<__attribute__((address_space(3))) u32*>(
          reinterpret_cast<uintptr_t>(l));
  const __attribute__((address_space(1))) u32* gp =
      reinterpret_cast<const __attribute__((address_space(1))) u32*>(
          reinterpret_cast<uintptr_t>(g));
  __builtin_amdgcn_global_load_lds(gp, lp, 16, 0, 0);
}

// k-chunk swizzle (round-5 verified: SQ_LDS_BANK_CONFLICT 4.19M -> 0).

// ---------------------------------------------------------------------------
// GEMM 128x128, double-buffered LDS, ONE barrier per K-iter (round-7
// verified: MfmaUtil 12->~20%, each GEMM <70us).
// EPI: 0=bias, 1=bias+gelu. OUTF: 0=bf16, 1=fp32 out.
// ---------------------------------------------------------------------------
template <int EPI, int OUTF>
__global__ __launch_bounds__(256) void gemm_bt(
    const u16* __restrict__ A, const u16* __restrict__ Bt,
    const float* __restrict__ bias, const float* res,
    u16* Cb, float* Cf, int M, int N, int K)
{
  __shared__ __attribute__((aligned(16))) u16 As[2][128 * 32];
  __shared__ __attribute__((aligned(16))) u16 Bs[2][128 * 32];
  const int tid  = threadIdx.x;
  const int wave = tid >> 6;
  const int lane = tid & 63;
  const int bm = blockIdx.y * 128;
  const int bn = blockIdx.x * 128;
  const int wr = (wave >> 1) * 64;
  const int wc = (wave & 1) * 64;
  const int lm = lane & 15;
  const int kq = lane >> 4;

  f32x4 acc[4][4];
#pragma unroll
  for (int i = 0; i < 4; ++i)
#pragma unroll
    for (int j = 0; j < 4; ++j) acc[i][j] = (f32x4){0.f, 0.f, 0.f, 0.f};

  const int srow = wave * 16 + (lane >> 2);
  const int kg   = (((lane & 3) - (srow >> 1)) & 3) * 8;
  const u16* gA = A  + (size_t)(bm + srow) * K + kg;
  const u16* gB = Bt + (size_t)(bn + srow) * K + kg;
  const int wb = (wave * 16) * 32;

  gld_lds16(gA, &As[0][wb]);
  gld_lds16(gA + (size_t)64 * K, &As[0][wb + 64 * 32]);
  gld_lds16(gB, &Bs[0][wb]);
  gld_lds16(gB + (size_t)64 * K, &Bs[0][wb + 64 * 32]);

  int buf = 0;
  for (int k0 = 0; k0 < K; k0 += 32, buf ^= 1) {
    __syncthreads();
    const int kn = k0 + 32;
    if (kn < K) {
      gld_lds16(gA + kn, &As[buf ^ 1][wb]);
      gld_lds16(gA + (size_t)64 * K + kn, &As[buf ^ 1][wb + 64 * 32]);
      gld_lds16(gB + kn, &Bs[buf ^ 1][wb]);
      gld_lds16(gB + (size_t)64 * K + kn, &Bs[buf ^ 1][wb + 64 * 32]);
    }

    short8 af[4], bfv[4];
#pragma unroll
    for (int ti = 0; ti < 4; ++ti) {
      const int Ra = wr + ti * 16 + lm;
      af[ti] = *(const short8*)&As[buf][Ra * 32 + (((kq + (Ra >> 1)) & 3) * 8)];
    }
#pragma unroll
    for (int tj = 0; tj < 4; ++tj) {
      const int Rb = wc + tj * 16 + lm;
      bfv[tj] = *(const short8*)&Bs[buf][Rb * 32 + (((kq + (Rb >> 1)) & 3) * 8)];
    }
#pragma unroll
    for (int ti = 0; ti < 4; ++ti)
#pragma unroll
      for (int tj = 0; tj < 4; ++tj)
        acc[ti][tj] = __builtin_amdgcn_mfma_f32_16x16x32_bf16(
            af[ti], bfv[tj], acc[ti][tj], 0, 0, 0);
  }

  const int r0 = (lane >> 4) * 4;
#pragma unroll
  for (int ti = 0; ti < 4; ++ti) {
#pragma unroll
    for (int r = 0; r < 4; ++r) {
      const int grow = bm + wr + ti * 16 + r0 + r;
#pragma unroll
      for (int tj = 0; tj < 4; ++tj) {
        const int gcol = bn + wc + tj * 16 + lm;
        const size_t idx = (size_t)grow * N + gcol;
        float v = acc[ti][tj][r] + bias[gcol];
        if (EPI == 1) v = 0.5f * v * (1.0f + erff(v * 0.70710678118654752f));
        if (OUTF) Cf[idx] = v;
        else      Cb[idx] = f2bf(v);
      }
    }
  }
}

// ---------------------------------------------------------------------------
// Split-K GEMM (Wo/W2: N=1024), double-buffered. Grid (8, 32, 2) = 512.
// ---------------------------------------------------------------------------
__global__ __launch_bounds__(256) void gemm_sp(
    const u16* __restrict__ A, const u16* __restrict__ Bt,
    u16* __restrict__ P0, u16* __restrict__ P1,
    int M, int N, int K, int KH)
{
  __shared__ __attribute__((aligned(16))) u16 As[2][128 * 32];
  __shared__ __attribute__((aligned(16))) u16 Bs[2][128 * 32];
  const int tid  = threadIdx.x;
  const int wave = tid >> 6;
  const int lane = tid & 63;
  const int bm = blockIdx.y * 128;
  const int bn = blockIdx.x * 128;
  const int kz = blockIdx.z;
  u16* P = kz ? P1 : P0;
  const int wr = (wave >> 1) * 64;
  const int wc = (wave & 1) * 64;
  const int lm = lane & 15;
  const int kq = lane >> 4;

  f32x4 acc[4][4];
#pragma unroll
  for (int i = 0; i < 4; ++i)
#pragma unroll
    for (int j = 0; j < 4; ++j) acc[i][j] = (f32x4){0.f, 0.f, 0.f, 0.f};

  const int srow = wave * 16 + (lane >> 2);
  const int kg   = (((lane & 3) - (srow >> 1)) & 3) * 8;
  const u16* gA = A  + (size_t)(bm + srow) * K + kz * KH + kg;
  const u16* gB = Bt + (size_t)(bn + srow) * K + kz * KH + kg;
  const int wb = (wave * 16) * 32;

  gld_lds16(gA, &As[0][wb]);
  gld_lds16(gA + (size_t)64 * K, &As[0][wb + 64 * 32]);
  gld_lds16(gB, &Bs[0][wb]);
  gld_lds16(gB + (size_t)64 * K, &Bs[0][wb + 64 * 32]);

  int buf = 0;
  for (int k0 = 0; k0 < KH; k0 += 32, buf ^= 1) {
    __syncthreads();
    const int kn = k0 + 32;
    if (kn < KH) {
      gld_lds16(gA + kn, &As[buf ^ 1][wb]);
      gld_lds16(gA + (size_t)64 * K + kn, &As[buf ^ 1][wb + 64 * 32]);
      gld_lds16(gB + kn, &Bs[buf ^ 1][wb]);
      gld_lds16(gB + (size_t)64 * K + kn, &Bs[buf ^ 1][wb + 64 * 32]);
    }

    short8 af[4], bfv[4];
#pragma unroll
    for (int ti = 0; ti < 4; ++ti) {
      const int Ra = wr + ti * 16 + lm;
      af[ti] = *(const short8*)&As[buf][Ra * 32 + (((kq + (Ra >> 1)) & 3) * 8)];
    }
#pragma unroll
    for (int tj = 0; tj < 4; ++tj) {
      const int Rb = wc + tj * 16 + lm;
      bfv[tj] = *(const short8*)&Bs[buf][Rb * 32 + (((kq + (Rb >> 1)) & 3) * 8)];
    }
#pragma unroll
    for (int ti = 0; ti < 4; ++ti)
#pragma unroll
      for (int tj = 0; tj < 4; ++tj)
        acc[ti][tj] = __builtin_amdgcn_mfma_f32_16x16x32_bf16(
            af[ti], bfv[tj], acc[ti][tj], 0, 0, 0);
  }

  const int r0 = (lane >> 4) * 4;
#pragma unroll
  for (int ti = 0; ti < 4; ++ti) {
#pragma unroll
    for (int r = 0; r < 4; ++r) {
      const int grow = bm + wr + ti * 16 + r0 + r;
#pragma unroll
      for (int tj = 0; tj < 4; ++tj) {
        const int gcol = bn + wc + tj * 16 + lm;
        P[(size_t)grow * N + gcol] = f2bf(acc[ti][tj][r]);
      }
    }
  }
}

// out[idx] = P0[idx] + P1[idx] + bias[col] + res[idx]   (N fixed = 1024)
__global__ __launch_bounds__(256) void reduce2(
    const u16* __restrict__ P0, const u16* __restrict__ P1,
    const float* __restrict__ bias, const float* res, float* out)
{
  const size_t base = ((size_t)blockIdx.x * 256 + threadIdx.x) * 8;
  const int col = (int)(base & 1023);
  uint4 p0 = *(const uint4*)(P0 + base);
  uint4 p1 = *(const uint4*)(P1 + base);
  float4 b0 = *(const float4*)(bias + col);
  float4 b1 = *(const float4*)(bias + col + 4);
  float4 r0 = *(const float4*)(res + base);
  float4 r1 = *(const float4*)(res + base + 4);
  float4 o0, o1;
  o0.x = bflo(p0.x) + bflo(p1.x) + b0.x + r0.x;
  o0.y = bfhi(p0.x) + bfhi(p1.x) + b0.y + r0.y;
  o0.z = bflo(p0.y) + bflo(p1.y) + b0.z + r0.z;
  o0.w = bfhi(p0.y) + bfhi(p1.y) + b0.w + r0.w;
  o1.x = bflo(p0.z) + bflo(p1.z) + b1.x + r1.x;
  o1.y = bfhi(p0.z) + bfhi(p1.z) + b1.y + r1.y;
  o1.z = bflo(p0.w) + bflo(p1.w) + b1.z + r1.z;
  o1.w = bfhi(p0.w) + bfhi(p1.w) + b1.w + r1.w;
  *(float4*)(out + base) = o0;
  *(float4*)(out + base + 4) = o1;
}

// ---------------------------------------------------------------------------
// LayerNorm: fp32 in, bf16 out. One block per row (D=1024).
// ---------------------------------------------------------------------------
__global__ __launch_bounds__(256) void ln_kernel(
    const float* __restrict__ x, const float* __restrict__ g,
    const float* __restrict__ b, u16* __restrict__ o)
{
  const int row = blockIdx.x;
  const int t = threadIdx.x;
  float4 v = *(const float4*)(x + (size_t)row * D_MODEL + t * 4);
  float s  = v.x + v.y + v.z + v.w;
  float ss = v.x * v.x + v.y * v.y + v.z * v.z + v.w * v.w;
#pragma unroll
  for (int off = 32; off > 0; off >>= 1) {
    s  += __shfl_down(s, off);
    ss += __shfl_down(ss, off);
  }
  __shared__ float sm[4], ssm[4], stat[2];
  if ((t & 63) == 0) { sm[t >> 6] = s; ssm[t >> 6] = ss; }
  __syncthreads();
  if (t == 0) {
    float S = sm[0] + sm[1] + sm[2] + sm[3];
    float SS = ssm[0] + ssm[1] + ssm[2] + ssm[3];
    float mu = S * (1.0f / 1024.0f);
    float var = SS * (1.0f / 1024.0f) - mu * mu;
    stat[0] = mu;
    stat[1] = rsqrtf(fmaxf(var, 0.0f) + 1e-5f);
  }
  __syncthreads();
  const float mu = stat[0], rstd = stat[1];
  float4 gg = *(const float4*)(g + t * 4);
  float4 bb = *(const float4*)(b + t * 4);
  u16 o0 = f2bf((v.x - mu) * rstd * gg.x + bb.x);
  u16 o1 = f2bf((v.y - mu) * rstd * gg.y + bb.y);
  u16 o2 = f2bf((v.z - mu) * rstd * gg.z + bb.z);
  u16 o3 = f2bf((v.w - mu) * rstd * gg.w + bb.w);
  uint2 w;
  w.x = (u32)o0 | ((u32)o1 << 16);
  w.y = (u32)o2 | ((u32)o3 << 16);
  *(uint2*)(o + (size_t)row * D_MODEL + t * 4) = w;
}

// ---------------------------------------------------------------------------
// Banded attention, MFMA flash style (rounds 4-7 verified).
// ---------------------------------------------------------------------------
__global__ __launch_bounds__(256) void attn_band(
    const u16* __restrict__ qkv, u16* __restrict__ out)
{
  const int t    = threadIdx.x;
  const int w    = t >> 6;
  const int lane = t & 63;
  const int m    = lane & 15;
  const int quad = lane >> 4;
  const int bh   = blockIdx.y;
  const int b    = bh >> 4, h = bh & 15;
  const int i0   = blockIdx.x * 64;
  const size_t bb = (size_t)b * S_LEN;

  __shared__ __attribute__((aligned(16))) u16 Ks[32 * 72];
  __shared__ __attribute__((aligned(16))) u16 Vt[64 * 40];
  __shared__ __attribute__((aligned(16))) u16 Ps[4][16 * 40];

  const u16* qrow = qkv + (bb + i0 + 16 * w + m) * 3072 + h * 64;
  const short8 aq0 = *(const short8*)(qrow + quad * 8);
  const short8 aq1 = *(const short8*)(qrow + 32 + quad * 8);

  f32x4 Ov[4];
#pragma unroll
  for (int td = 0; td < 4; ++td) Ov[td] = (f32x4){0.f, 0.f, 0.f, 0.f};
  float mP[4] = {-1e30f, -1e30f, -1e30f, -1e30f};
  float lS[4] = {0.f, 0.f, 0.f, 0.f};

  const int iB = i0 + 16 * w + quad * 4;

  const int lo = max(32, i0 - 128);
  const int hi = min(S_LEN, i0 + 192);
  const int nChunks = 1 + (hi - lo) / 32;

  const int skr = t >> 3;
  const int skc = (t & 7) * 8;

  for (int c = 0; c < nChunks; ++c) {
    const int j0 = (c == 0) ? 0 : lo + (c - 1) * 32;
    __syncthreads();
    {
      const u16* src = qkv + (bb + j0 + skr) * 3072 + 1024 + h * 64 + skc;
      uint4 kk = *(const uint4*)src;
      uint4 vv = *(const uint4*)(src + 1024);
      *(uint4*)&Ks[skr * 72 + skc] = kk;
      const u16 vs[8] = {
        (u16)(vv.x & 0xffffu), (u16)(vv.x >> 16),
        (u16)(vv.y & 0xffffu), (u16)(vv.y >> 16),
        (u16)(vv.z & 0xffffu), (u16)(vv.z >> 16),
        (u16)(vv.w & 0xffffu), (u16)(vv.w >> 16)};
#pragma unroll
      for (int i = 0; i < 8; ++i) Vt[(skc + i) * 40 + skr] = vs[i];
    }
    __syncthreads();

    const short8 b00 = *(const short8*)&Ks[m * 72 + quad * 8];
    const short8 b01 = *(const short8*)&Ks[m * 72 + 32 + quad * 8];
    const short8 b10 = *(const short8*)&Ks[(16 + m) * 72 + quad * 8];
    const short8 b11 = *(const short8*)&Ks[(16 + m) * 72 + 32 + quad * 8];
    f32x4 s0 = (f32x4){0.f, 0.f, 0.f, 0.f};
    f32x4 s1 = (f32x4){0.f, 0.f, 0.f, 0.f};
    s0 = __builtin_amdgcn_mfma_f32_16x16x32_bf16(aq0, b00, s0, 0, 0, 0);
    s0 = __builtin_amdgcn_mfma_f32_16x16x32_bf16(aq1, b01, s0, 0, 0, 0);
    s1 = __builtin_amdgcn_mfma_f32_16x16x32_bf16(aq0, b10, s1, 0, 0, 0);
    s1 = __builtin_amdgcn_mfma_f32_16x16x32_bf16(aq1, b11, s1, 0, 0, 0);

    const int jA = j0 + m, jB = j0 + 16 + m;
#pragma unroll
    for (int r = 0; r < 4; ++r) {
      const int iG = iB + r;
      const int da = iG - jA, db = iG - jB;
      s0[r] = ((jA < 16) || (da >= -128 && da <= 128)) ? s0[r] * 0.125f : -1e30f;
      s1[r] = ((jB < 16) || (db >= -128 && db <= 128)) ? s1[r] * 0.125f : -1e30f;
    }

    float al[4];
#pragma unroll
    for (int r = 0; r < 4; ++r) {
      float mx = fmaxf(s0[r], s1[r]);
      mx = fmaxf(mx, __shfl_xor(mx, 1, 16));
      mx = fmaxf(mx, __shfl_xor(mx, 2, 16));
      mx = fmaxf(mx, __shfl_xor(mx, 4, 16));
      mx = fmaxf(mx, __shfl_xor(mx, 8, 16));
      const float mn = fmaxf(mP[r], mx);
      al[r] = __expf(mP[r] - mn);
      mP[r] = mn;
      const float p0 = __expf(s0[r] - mn);
      const float p1 = __expf(s1[r] - mn);
      float ps = p0 + p1;
      ps += __shfl_xor(ps, 1, 16);
      ps += __shfl_xor(ps, 2, 16);
      ps += __shfl_xor(ps, 4, 16);
      ps += __shfl_xor(ps, 8, 16);
      lS[r] = lS[r] * al[r] + ps;
      Ps[w][(quad * 4 + r) * 40 + m]      = f2bf(p0);
      Ps[w][(quad * 4 + r) * 40 + 16 + m] = f2bf(p1);
    }
#pragma unroll
    for (int td = 0; td < 4; ++td)
#pragma unroll
      for (int r = 0; r < 4; ++r) Ov[td][r] *= al[r];

    const short8 pa = *(const short8*)&Ps[w][m * 40 + quad * 8];
#pragma unroll
    for (int td = 0; td < 4; ++td) {
      const short8 bv = *(const short8*)&Vt[(td * 16 + m) * 40 + quad * 8];
      Ov[td] = __builtin_amdgcn_mfma_f32_16x16x32_bf16(pa, bv, Ov[td], 0, 0, 0);
    }
  }

  if (i0 + 16 * w >= 16) {
    float inv[4];
#pragma unroll
    for (int r = 0; r < 4; ++r) inv[r] = 1.0f / lS[r];
#pragma unroll
    for (int td = 0; td < 4; ++td)
#pragma unroll
      for (int r = 0; r < 4; ++r)
        out[(bb + iB + r) * 1024 + h * 64 + td * 16 + m] =
            f2bf(Ov[td][r] * inv[r]);
  }
}

// ---------------------------------------------------------------------------
// Global rows (i<16), MFMA split-K replacement for the old scalar kernel
// (round-7 profile: 70us, MfmaUtil=0, worst-case uncoalesced K reads).
// attn_gpart: grid (8 kb, 32 bh). Wave w owns keys [kb*256+w*64, +64) in two
// 32-key chunks. Staging is wave-private (same-wave LDS write->read, no
// barrier — pattern validated by Ps in attn_band). No mask: rows i<16 attend
// to all keys. Writes unnormalized partial (O[16][64], m[16], l[16]) fp32.
// attn_gcombine: grid (32 bh): online-softmax merge of 32 partials.
// ---------------------------------------------------------------------------
__global__ __launch_bounds__(256) void attn_gpart(
    const u16* __restrict__ qkv, float* __restrict__ Obuf,
    float* __restrict__ mbuf, float* __restrict__ lbuf)
{
  const int t    = threadIdx.x;
  const int w    = t >> 6;
  const int lane = t & 63;
  const int m    = lane & 15;
  const int quad = lane >> 4;
  const int kb   = blockIdx.x;   // 0..7
  const int bh   = blockIdx.y;   // 0..31
  const int b    = bh >> 4, h = bh & 15;
  const size_t bb = (size_t)b * S_LEN;

  __shared__ __attribute__((aligned(16))) u16 Ks[4][32 * 72];
  __shared__ __attribute__((aligned(16))) u16 Vt[4][64 * 40];
  __shared__ __attribute__((aligned(16))) u16 Ps[4][16 * 40];

  // Q: the 16 global rows, head h (A-layout: A[m][k=quad*8+j])
  const u16* qrow = qkv + (bb + m) * 3072 + h * 64;
  const short8 aq0 = *(const short8*)(qrow + quad * 8);
  const short8 aq1 = *(const short8*)(qrow + 32 + quad * 8);

  f32x4 Ov[4];
#pragma unroll
  for (int td = 0; td < 4; ++td) Ov[td] = (f32x4){0.f, 0.f, 0.f, 0.f};
  float mP[4] = {-1e30f, -1e30f, -1e30f, -1e30f};
  float lS[4] = {0.f, 0.f, 0.f, 0.f};

  const int srow = lane >> 1;        // staging: key row 0..31
  const int sd   = (lane & 1) * 32;  // staging: d half

  for (int c = 0; c < 2; ++c) {
    const int j0 = kb * 256 + w * 64 + c * 32;
    {  // wave-private K/V staging (32 keys x 64 d)
      const u16* src = qkv + (bb + j0 + srow) * 3072 + 1024 + h * 64 + sd;
      uint4 k0 = *(const uint4*)(src);
      uint4 k1 = *(const uint4*)(src + 8);
      uint4 k2 = *(const uint4*)(src + 16);
      uint4 k3 = *(const uint4*)(src + 24);
      *(uint4*)&Ks[w][srow * 72 + sd]      = k0;
      *(uint4*)&Ks[w][srow * 72 + sd + 8]  = k1;
      *(uint4*)&Ks[w][srow * 72 + sd + 16] = k2;
      *(uint4*)&Ks[w][srow * 72 + sd + 24] = k3;
#pragma unroll
      for (int q4 = 0; q4 < 4; ++q4) {
        uint4 vv = *(const uint4*)(src + 1024 + q4 * 8);
        const u16 vs[8] = {
          (u16)(vv.x & 0xffffu), (u16)(vv.x >> 16),
          (u16)(vv.y & 0xffffu), (u16)(vv.y >> 16),
          (u16)(vv.z & 0xffffu), (u16)(vv.z >> 16),
          (u16)(vv.w & 0xffffu), (u16)(vv.w >> 16)};
#pragma unroll
        for (int i = 0; i < 8; ++i)
          Vt[w][(sd + q4 * 8 + i) * 40 + srow] = vs[i];
      }
    }

    const short8 b00 = *(const short8*)&Ks[w][m * 72 + quad * 8];
    const short8 b01 = *(const short8*)&Ks[w][m * 72 + 32 + quad * 8];
    const short8 b10 = *(const short8*)&Ks[w][(16 + m) * 72 + quad * 8];
    const short8 b11 = *(const short8*)&Ks[w][(16 + m) * 72 + 32 + quad * 8];
    f32x4 s0 = (f32x4){0.f, 0.f, 0.f, 0.f};
    f32x4 s1 = (f32x4){0.f, 0.f, 0.f, 0.f};
    s0 = __builtin_amdgcn_mfma_f32_16x16x32_bf16(aq0, b00, s0, 0, 0, 0);
    s0 = __builtin_amdgcn_mfma_f32_16x16x32_bf16(aq1, b01, s0, 0, 0, 0);
    s1 = __builtin_amdgcn_mfma_f32_16x16x32_bf16(aq0, b10, s1, 0, 0, 0);
    s1 = __builtin_amdgcn_mfma_f32_16x16x32_bf16(aq1, b11, s1, 0, 0, 0);

    float al[4];
#pragma unroll
    for (int r = 0; r < 4; ++r) {
      const float v0 = s0[r] * 0.125f, v1 = s1[r] * 0.125f;
      float mx = fmaxf(v0, v1);
      mx = fmaxf(mx, __shfl_xor(mx, 1, 16));
      mx = fmaxf(mx, __shfl_xor(mx, 2, 16));
      mx = fmaxf(mx, __shfl_xor(mx, 4, 16));
      mx = fmaxf(mx, __shfl_xor(mx, 8, 16));
      const float mn = fmaxf(mP[r], mx);
      al[r] = __expf(mP[r] - mn);
      mP[r] = mn;
      const float p0 = __expf(v0 - mn);
      const float p1 = __expf(v1 - mn);
      float ps = p0 + p1;
      ps += __shfl_xor(ps, 1, 16);
      ps += __shfl_xor(ps, 2, 16);
      ps += __shfl_xor(ps, 4, 16);
      ps += __shfl_xor(ps, 8, 16);
      lS[r] = lS[r] * al[r] + ps;
      Ps[w][(quad * 4 + r) * 40 + m]      = f2bf(p0);
      Ps[w][(quad * 4 + r) * 40 + 16 + m] = f2bf(p1);
    }
#pragma unroll
    for (int td = 0; td < 4; ++td)
#pragma unroll
      for (int r = 0; r < 4; ++r) Ov[td][r] *= al[r];

    const short8 pa = *(const short8*)&Ps[w][m * 40 + quad * 8];
#pragma unroll
    for (int td = 0; td < 4; ++td) {
      const short8 bv = *(const short8*)&Vt[w][(td * 16 + m) * 40 + quad * 8];
      Ov[td] = __builtin_amdgcn_mfma_f32_16x16x32_bf16(pa, bv, Ov[td], 0, 0, 0);
    }
  }

  // write unnormalized partial p = kb*4 + w
  const int p = kb * 4 + w;
  const size_t ob = ((size_t)(bh * 32 + p)) * 16 * 64;
#pragma unroll
  for (int td = 0; td < 4; ++td)
#pragma unroll
    for (int r = 0; r < 4; ++r)
      Obuf[ob + (size_t)(quad * 4 + r) * 64 + td * 16 + m] = Ov[td][r];
  if (m == 0) {
    const int mb = (bh * 32 + p) * 16;
#pragma unroll
    for (int r = 0; r < 4; ++r) {
      mbuf[mb + quad * 4 + r] = mP[r];
      lbuf[mb + quad * 4 + r] = lS[r];
    }
  }
}

__global__ __launch_bounds__(256) void attn_gcombine(
    const float* __restrict__ Obuf, const float* __restrict__ mbuf,
    const float* __restrict__ lbuf, u16* __restrict__ out)
{
  const int bh = blockIdx.x;  // 0..31
  const int b  = bh >> 4, h = bh & 15;
  const int t  = threadIdx.x;
  const int q  = t >> 4;          // global row 0..15
  const int d0 = (t & 15) * 4;    // d 0..63 step 4
  const int mb = bh * 32 * 16;

  float mv[32];
  float M = -1e30f;
#pragma unroll
  for (int p = 0; p < 32; ++p) {
    mv[p] = mbuf[mb + p * 16 + q];
    M = fmaxf(M, mv[p]);
  }
  float L = 0.f;
  float4 acc = {0.f, 0.f, 0.f, 0.f};
#pragma unroll
  for (int p = 0; p < 32; ++p) {
    const float wp = __expf(mv[p] - M);
    L += lbuf[mb + p * 16 + q] * wp;
    float4 o = *(const float4*)&Obuf[(((size_t)(bh * 32 + p)) * 16 + q) * 64 + d0];
    acc.x += wp * o.x; acc.y += wp * o.y;
    acc.z += wp * o.z; acc.w += wp * o.w;
  }
  const float inv = 1.0f / L;
  uint2 wv;
  wv.x = (u32)f2bf(acc.x * inv) | ((u32)f2bf(acc.y * inv) << 16);
  wv.y = (u32)f2bf(acc.z * inv) | ((u32)f2bf(acc.w * inv) << 16);
  *(uint2*)(out + ((size_t)b * S_LEN + q) * 1024 + h * 64 + d0) = wv;
}

// ---------------------------------------------------------------------------
// Consolidated prep: 6 weight transposes (fp32 -> bf16) + bias concat.
// ---------------------------------------------------------------------------
__global__ __launch_bounds__(256) void prep_all(
    const float* __restrict__ Wq, const float* __restrict__ Wk,
    const float* __restrict__ Wv, const float* __restrict__ Wo,
    const float* __restrict__ W1, const float* __restrict__ W2,
    const float* __restrict__ bq, const float* __restrict__ bk,
    const float* __restrict__ bv,
    u16* __restrict__ WQKVT, u16* __restrict__ WOT,
    u16* __restrict__ W1T, u16* __restrict__ W2T,
    float* __restrict__ BQKV)
{
  const int gb = blockIdx.x;
  const int t = threadIdx.x;
  if (gb >= 3072) {  // concat
    const int i = (gb - 3072) * 256 + t;
    if (i < 1024) BQKV[i] = bq[i];
    else if (i < 2048) BQKV[i] = bk[i - 1024];
    else BQKV[i] = bv[i - 2048];
    return;
  }
  const float* in; u16* outp; int R, Cc, bx, by;
  if (gb < 1024) {
    const int seg = gb >> 8, local = gb & 255;
    bx = local & 15; by = local >> 4; R = 1024; Cc = 1024;
    in   = (seg == 0) ? Wq : (seg == 1) ? Wk : (seg == 2) ? Wv : Wo;
    outp = (seg < 3) ? WQKVT + (size_t)seg * 1024 * 1024 : WOT;
  } else if (gb < 2048) {
    const int local = gb - 1024;
    bx = local & 63; by = local >> 6; R = 1024; Cc = 4096;
    in = W1; outp = W1T;
  } else {
    const int local = gb - 2048;
    bx = local & 15; by = local >> 4; R = 4096; Cc = 1024;
    in = W2; outp = W2T;
  }

  __shared__ u16 tile[64][65];
  const int tr = by * 64, tc = bx * 64;
  const int lr = t >> 2, lc0 = (t & 3) * 16;
  const float* src = in + (size_t)(tr + lr) * Cc + tc + lc0;
  float4 a0 = *(const float4*)(src);
  float4 a1 = *(const float4*)(src + 4);
  float4 a2 = *(const float4*)(src + 8);
  float4 a3 = *(const float4*)(src + 12);
  const float vals[16] = {a0.x, a0.y, a0.z, a0.w, a1.x, a1.y, a1.z, a1.w,
                          a2.x, a2.y, a2.z, a2.w, a3.x, a3.y, a3.z, a3.w};
#pragma unroll
  for (int q = 0; q < 16; ++q) tile[lr][lc0 + q] = f2bf(vals[q]);
  __syncthreads();
  u16* dst = outp + (size_t)(tc + lr) * R + tr + lc0;
  u32 w[8];
#pragma unroll
  for (int q = 0; q < 8; ++q)
    w[q] = (u32)tile[lc0 + 2 * q][lr] | ((u32)tile[lc0 + 2 * q + 1][lr] << 16);
  uint4 s0; s0.x = w[0]; s0.y = w[1]; s0.z = w[2]; s0.w = w[3];
  uint4 s1; s1.x = w[4]; s1.y = w[5]; s1.z = w[6]; s1.w = w[7];
  *(uint4*)dst = s0;
  *(uint4*)(dst + 8) = s1;
}

// ---------------------------------------------------------------------------
// workspace layout (bytes) — ~64 MB (validated rounds 3-7).
// Global-attn partials live in XN (dead during attention: LN1 output already
// consumed by the QKV GEMM; LN2 rewrites XN later). Split-K partials: Wo ->
// QKV region; W2 -> W1T + XN (both dead by then).
// ---------------------------------------------------------------------------
static const size_t OFF_WQKVT = 0;                                   // bf16 [3072][1024]
static const size_t OFF_WOT   = OFF_WQKVT + (size_t)3072 * 1024 * 2; // bf16 [1024][1024]
static const size_t OFF_W1T   = OFF_WOT   + (size_t)1024 * 1024 * 2; // bf16 [4096][1024]
static const size_t OFF_W2T   = OFF_W1T   + (size_t)4096 * 1024 * 2; // bf16 [1024][4096]
static const size_t OFF_BQKV  = OFF_W2T   + (size_t)1024 * 4096 * 2; // fp32 [3072]
static const size_t OFF_XN    = OFF_BQKV  + 16384;                   // bf16 [4096][1024]
static const size_t OFF_QKV   = OFF_XN    + (size_t)4096 * 1024 * 2; // bf16 [4096][3072]
static const size_t OFF_AO    = OFF_QKV   + (size_t)4096 * 3072 * 2; // bf16 [4096][1024]
static const size_t OFF_H     = OFF_QKV;  // bf16 [4096][4096], aliases QKV+AO

extern "C" void kernel_launch(void* const* d_in, const int* in_sizes, int n_in,
                              void* d_out, int out_size, void* d_ws, size_t ws_size,
                              hipStream_t stream)
{
  const float* x   = (const float*)d_in[0];
  const float* Wq  = (const float*)d_in[1];
  const float* bq  = (const float*)d_in[2];
  const float* Wk  = (const float*)d_in[3];
  const float* bk  = (const float*)d_in[4];
  const float* Wv  = (const float*)d_in[5];
  const float* bv  = (const float*)d_in[6];
  const float* Wo  = (const float*)d_in[7];
  const float* bo  = (const float*)d_in[8];
  const float* g1  = (const float*)d_in[9];
  const float* be1 = (const float*)d_in[10];
  const float* W1  = (const float*)d_in[11];
  const float* b1  = (const float*)d_in[12];
  const float* W2  = (const float*)d_in[13];
  const float* b2  = (const float*)d_in[14];
  const float* g2  = (const float*)d_in[15];
  const float* be2 = (const float*)d_in[16];
  float* outf = (float*)d_out;
  char* ws = (char*)d_ws;

  u16*   WQKVT = (u16*)(ws + OFF_WQKVT);
  u16*   WOT   = (u16*)(ws + OFF_WOT);
  u16*   W1T   = (u16*)(ws + OFF_W1T);
  u16*   W2T   = (u16*)(ws + OFF_W2T);
  float* BQKV  = (float*)(ws + OFF_BQKV);
  u16*   XN    = (u16*)(ws + OFF_XN);
  u16*   QKV   = (u16*)(ws + OFF_QKV);
  u16*   AO    = (u16*)(ws + OFF_AO);
  u16*   Hbuf  = (u16*)(ws + OFF_H);
  float* X1    = outf;  // fp32 residual stream #2 lives in d_out
  u16* PWo0 = (u16*)(ws + OFF_QKV);
  u16* PWo1 = PWo0 + (size_t)4096 * 1024;
  u16* PW20 = (u16*)(ws + OFF_W1T);
  u16* PW21 = (u16*)(ws + OFF_XN);
  // global-attn partials in XN region (fp32): O[32bh][32p][16q][64d] + m/l
  float* GO = (float*)(ws + OFF_XN);
  float* GM = GO + (size_t)32 * 32 * 16 * 64;   // 4 MB of floats
  float* GL = GM + 32 * 32 * 16;

  const dim3 blk(256);
  prep_all<<<dim3(3084), blk, 0, stream>>>(Wq, Wk, Wv, Wo, W1, W2, bq, bk, bv,
                                           WQKVT, WOT, W1T, W2T, BQKV);

  // attention sublayer
  ln_kernel<<<dim3(ROWS), blk, 0, stream>>>(x, g1, be1, XN);
  gemm_bt<0, 0><<<dim3(24, 32), blk, 0, stream>>>(XN, WQKVT, BQKV, nullptr,
                                                  QKV, nullptr, ROWS, 3072, 1024);
  attn_band<<<dim3(32, 32), blk, 0, stream>>>(QKV, AO);
  attn_gpart<<<dim3(8, 32), blk, 0, stream>>>(QKV, GO, GM, GL);
  attn_gcombine<<<dim3(32), blk, 0, stream>>>(GO, GM, GL, AO);
  gemm_sp<<<dim3(8, 32, 2), blk, 0, stream>>>(AO, WOT, PWo0, PWo1,
                                              ROWS, 1024, 1024, 512);
  reduce2<<<dim3(2048), blk, 0, stream>>>(PWo0, PWo1, bo, x, X1);

  // FFN sublayer
  ln_kernel<<<dim3(ROWS), blk, 0, stream>>>(X1, g2, be2, XN);
  gemm_bt<1, 0><<<dim3(32, 32), blk, 0, stream>>>(XN, W1T, b1, nullptr,
                                                  Hbuf, nullptr, ROWS, 4096, 1024);
  gemm_sp<<<dim3(8, 32, 2), blk, 0, stream>>>(Hbuf, W2T, PW20, PW21,
                                              ROWS, 1024, 4096, 2048);
  reduce2<<<dim3(2048), blk, 0, stream>>>(PW20, PW21, b2, X1, outf);
}